// Round 1
// baseline (699.424 us; speedup 1.0000x reference)
//
#include <hip/hip_runtime.h>
#include <math.h>

// Problem constants (from reference)
constexpr int N_NODES = 50000;
constexpr int N_EDGES = 800000;
constexpr int TOT_E   = N_EDGES + N_NODES;   // + self loops
constexpr int HCv     = 256;                 // H*C
constexpr int Cv      = 128;                 // per-head channels

// ---------------- CSR build ----------------

__global__ void count_deg_k(const int* __restrict__ ei, int* __restrict__ deg) {
    int e = blockIdx.x * blockDim.x + threadIdx.x;
    if (e >= TOT_E) return;
    int dst = (e < N_EDGES) ? ei[N_EDGES + e] : (e - N_EDGES);
    atomicAdd(&deg[dst], 1);
}

// single block of 256 threads: exclusive scan of deg -> rowptr, and deg buffer
// becomes the scatter cursor (initialized to row starts).
__global__ void scan_k(int* __restrict__ deg_cursor, int* __restrict__ rowptr) {
    __shared__ int sums[256];
    int t = threadIdx.x;
    const int chunk = (N_NODES + 255) / 256;
    int s = 0;
    for (int i = 0; i < chunk; ++i) {
        int idx = t * chunk + i;
        if (idx < N_NODES) s += deg_cursor[idx];
    }
    sums[t] = s;
    __syncthreads();
    for (int off = 1; off < 256; off <<= 1) {
        int v = (t >= off) ? sums[t - off] : 0;
        __syncthreads();
        sums[t] += v;
        __syncthreads();
    }
    int run = (t == 0) ? 0 : sums[t - 1];
    for (int i = 0; i < chunk; ++i) {
        int idx = t * chunk + i;
        if (idx < N_NODES) {
            int d = deg_cursor[idx];
            rowptr[idx] = run;
            deg_cursor[idx] = run;   // cursor for scatter
            run += d;
        }
    }
    if (t == 255) rowptr[N_NODES] = run;
}

__global__ void scatter_k(const int* __restrict__ ei, int* __restrict__ cursor,
                          int* __restrict__ colv) {
    int e = blockIdx.x * blockDim.x + threadIdx.x;
    if (e >= TOT_E) return;
    int srcv, dstv;
    if (e < N_EDGES) { srcv = ei[e]; dstv = ei[N_EDGES + e]; }
    else             { srcv = dstv = e - N_EDGES; }
    int pos = atomicAdd(&cursor[dstv], 1);
    colv[pos] = srcv;
}

// ---------------- fp32 tiled GEMM: C[M x N] = A[M x K] @ B[K x N] ----------------
// BM=BN=64, BK=16, 256 threads, 4x4 per thread. N % 64 == 0, K % 16 == 0 assumed.

__global__ __launch_bounds__(256) void gemm_k(const float* __restrict__ A,
                                              const float* __restrict__ B,
                                              float* __restrict__ C,
                                              int M, int K, int N) {
    __shared__ float As[16][68];   // As[k][row]  (transposed A tile)
    __shared__ float Bs[16][68];   // Bs[k][col]
    const int tid = threadIdx.x;
    const int tx = tid & 15;       // col group (x4)
    const int ty = tid >> 4;       // row group (x4)
    const int row0 = blockIdx.x * 64;
    const int col0 = blockIdx.y * 64;
    float acc[4][4] = {};
    for (int k0 = 0; k0 < K; k0 += 16) {
#pragma unroll
        for (int l = 0; l < 4; ++l) {           // A tile: 64 rows x 16 k
            int idx = tid + l * 256;
            int r = idx >> 4, c = idx & 15;
            int row = row0 + r;
            As[c][r] = (row < M) ? A[row * K + k0 + c] : 0.f;
        }
#pragma unroll
        for (int l = 0; l < 4; ++l) {           // B tile: 16 k x 64 cols
            int idx = tid + l * 256;
            int r = idx >> 6, c = idx & 63;
            Bs[r][c] = B[(k0 + r) * N + col0 + c];
        }
        __syncthreads();
#pragma unroll
        for (int k = 0; k < 16; ++k) {
            float a[4], b[4];
#pragma unroll
            for (int i = 0; i < 4; ++i) a[i] = As[k][ty * 4 + i];
#pragma unroll
            for (int j = 0; j < 4; ++j) b[j] = Bs[k][tx * 4 + j];
#pragma unroll
            for (int i = 0; i < 4; ++i)
#pragma unroll
                for (int j = 0; j < 4; ++j)
                    acc[i][j] += a[i] * b[j];
        }
        __syncthreads();
    }
#pragma unroll
    for (int i = 0; i < 4; ++i) {
        int row = row0 + ty * 4 + i;
        if (row < M) {
            float4 v = make_float4(acc[i][0], acc[i][1], acc[i][2], acc[i][3]);
            *reinterpret_cast<float4*>(&C[row * N + col0 + tx * 4]) = v;
        }
    }
}

// ---------------- attention coefficients: a_s[n,h], a_d[n,h] ----------------
// one wave per (node, head)

__global__ void att_k(const float* __restrict__ h, const float* __restrict__ att_src,
                      const float* __restrict__ att_dst, float* __restrict__ a_s,
                      float* __restrict__ a_d) {
    int lane = threadIdx.x & 63;
    int pair = blockIdx.x * 4 + (threadIdx.x >> 6);
    if (pair >= N_NODES * 2) return;
    int node = pair >> 1, hh = pair & 1;
    const float* hr = h + (size_t)node * HCv + hh * Cv;
    const float* as = att_src + hh * Cv;
    const float* ad = att_dst + hh * Cv;
    float s = 0.f, d = 0.f;
    for (int c = lane; c < Cv; c += 64) {
        float v = hr[c];
        s += v * as[c];
        d += v * ad[c];
    }
#pragma unroll
    for (int off = 32; off; off >>= 1) {
        s += __shfl_down(s, off);
        d += __shfl_down(d, off);
    }
    if (lane == 0) { a_s[pair] = s; a_d[pair] = d; }
}

// ---------------- aggregation: one wave per destination node ----------------
// lane owns channels [lane*4, lane*4+4); head = lane>>5

__device__ __forceinline__ float lrelu(float x) { return x > 0.f ? x : 0.2f * x; }

template <bool TANH>
__global__ void agg_k(const float* __restrict__ h, const float* __restrict__ a_s,
                      const float* __restrict__ a_d, const int* __restrict__ rowptr,
                      const int* __restrict__ colv, const float* __restrict__ bias,
                      float* __restrict__ out) {
    int lane = threadIdx.x & 63;
    int node = blockIdx.x * 4 + (threadIdx.x >> 6);
    if (node >= N_NODES) return;
    int beg = rowptr[node], end = rowptr[node + 1];
    float ad0 = a_d[node * 2], ad1 = a_d[node * 2 + 1];

    // pass 1: per-head max of leaky-relu logits over incoming edges
    float m0 = -INFINITY, m1 = -INFINITY;
    for (int e = beg + lane; e < end; e += 64) {
        int s = colv[e];
        m0 = fmaxf(m0, lrelu(a_s[s * 2] + ad0));
        m1 = fmaxf(m1, lrelu(a_s[s * 2 + 1] + ad1));
    }
#pragma unroll
    for (int off = 32; off; off >>= 1) {
        m0 = fmaxf(m0, __shfl_xor(m0, off));
        m1 = fmaxf(m1, __shfl_xor(m1, off));
    }
    // pass 2: denominators
    float s0 = 0.f, s1 = 0.f;
    for (int e = beg + lane; e < end; e += 64) {
        int s = colv[e];
        s0 += __expf(lrelu(a_s[s * 2] + ad0) - m0);
        s1 += __expf(lrelu(a_s[s * 2 + 1] + ad1) - m1);
    }
#pragma unroll
    for (int off = 32; off; off >>= 1) {
        s0 += __shfl_xor(s0, off);
        s1 += __shfl_xor(s1, off);
    }
    float inv0 = 1.f / (s0 + 1e-16f), inv1 = 1.f / (s1 + 1e-16f);

    const int head = lane >> 5;
    const float mh  = head ? m1 : m0;
    const float ih  = head ? inv1 : inv0;
    const float adh = head ? ad1 : ad0;
    const int cbase = lane * 4;

    // pass 3: all lanes walk every edge; per-lane float4 channel accumulate
    float acc0 = 0.f, acc1 = 0.f, acc2 = 0.f, acc3 = 0.f;
    for (int e = beg; e < end; ++e) {
        int s = colv[e];
        float l = lrelu(a_s[s * 2 + head] + adh);
        float alpha = __expf(l - mh) * ih;
        const float4 hv = *reinterpret_cast<const float4*>(h + (size_t)s * HCv + cbase);
        acc0 += hv.x * alpha;
        acc1 += hv.y * alpha;
        acc2 += hv.z * alpha;
        acc3 += hv.w * alpha;
    }
    float4 o;
    o.x = acc0 + bias[cbase + 0];
    o.y = acc1 + bias[cbase + 1];
    o.z = acc2 + bias[cbase + 2];
    o.w = acc3 + bias[cbase + 3];
    if (TANH) {
        o.x = tanhf(o.x); o.y = tanhf(o.y); o.z = tanhf(o.z); o.w = tanhf(o.w);
    }
    *reinterpret_cast<float4*>(out + (size_t)node * HCv + cbase) = o;
}

// ---------------- final linear (256 -> 2) + softmax ----------------

__global__ void final_k(const float* __restrict__ h, const float* __restrict__ Wl,
                        const float* __restrict__ bl, float* __restrict__ out) {
    int lane = threadIdx.x & 63;
    int node = blockIdx.x * 4 + (threadIdx.x >> 6);
    if (node >= N_NODES) return;
    const float* hr = h + (size_t)node * HCv;
    float o0 = 0.f, o1 = 0.f;
    for (int k = lane; k < HCv; k += 64) {
        float v = hr[k];
        o0 += v * Wl[k * 2 + 0];
        o1 += v * Wl[k * 2 + 1];
    }
#pragma unroll
    for (int off = 32; off; off >>= 1) {
        o0 += __shfl_down(o0, off);
        o1 += __shfl_down(o1, off);
    }
    if (lane == 0) {
        o0 += bl[0];
        o1 += bl[1];
        float mx = fmaxf(o0, o1);
        float e0 = __expf(o0 - mx), e1 = __expf(o1 - mx);
        float inv = 1.f / (e0 + e1);
        out[node * 2 + 0] = e0 * inv;
        out[node * 2 + 1] = e1 * inv;
    }
}

// ---------------- launch ----------------

extern "C" void kernel_launch(void* const* d_in, const int* in_sizes, int n_in,
                              void* d_out, int out_size, void* d_ws, size_t ws_size,
                              hipStream_t stream) {
    const float* x        = (const float*)d_in[0];
    const int*   ei       = (const int*)d_in[1];
    const float* W0       = (const float*)d_in[2];
    const float* att_src0 = (const float*)d_in[3];
    const float* att_dst0 = (const float*)d_in[4];
    const float* b0       = (const float*)d_in[5];
    const float* W1       = (const float*)d_in[6];
    const float* att_src1 = (const float*)d_in[7];
    const float* att_dst1 = (const float*)d_in[8];
    const float* b1       = (const float*)d_in[9];
    const float* Wl       = (const float*)d_in[10];
    const float* bl       = (const float*)d_in[11];
    float* out = (float*)d_out;

    // workspace layout
    float* bufA = (float*)d_ws;                       // N * 256
    float* bufB = bufA + (size_t)N_NODES * HCv;       // N * 256
    float* a_s  = bufB + (size_t)N_NODES * HCv;       // N * 2
    float* a_d  = a_s + N_NODES * 2;                  // N * 2
    int* rowptr = (int*)(a_d + N_NODES * 2);          // N + 1
    int* cursor = rowptr + (N_NODES + 1);             // N   (deg, then cursor)
    int* colv   = cursor + N_NODES;                   // E + N

    // ---- CSR build (once per launch; reused by both layers) ----
    hipMemsetAsync(cursor, 0, N_NODES * sizeof(int), stream);
    int eb = (TOT_E + 255) / 256;
    count_deg_k<<<eb, 256, 0, stream>>>(ei, cursor);
    scan_k<<<1, 256, 0, stream>>>(cursor, rowptr);
    scatter_k<<<eb, 256, 0, stream>>>(ei, cursor, colv);

    dim3 ggrid((N_NODES + 63) / 64, HCv / 64);
    int nb4 = (N_NODES * 2 + 3) / 4;   // wave-per-pair blocks
    int nn4 = (N_NODES + 3) / 4;       // wave-per-node blocks

    // ---- layer 0 ----
    gemm_k<<<ggrid, 256, 0, stream>>>(x, W0, bufA, N_NODES, 128, HCv);
    att_k<<<nb4, 256, 0, stream>>>(bufA, att_src0, att_dst0, a_s, a_d);
    agg_k<true><<<nn4, 256, 0, stream>>>(bufA, a_s, a_d, rowptr, colv, b0, bufB);

    // ---- layer 1 ----
    gemm_k<<<ggrid, 256, 0, stream>>>(bufB, W1, bufA, N_NODES, HCv, HCv);
    att_k<<<nb4, 256, 0, stream>>>(bufA, att_src1, att_dst1, a_s, a_d);
    agg_k<false><<<nn4, 256, 0, stream>>>(bufA, a_s, a_d, rowptr, colv, b1, bufB);

    // ---- final linear + softmax ----
    final_k<<<nn4, 256, 0, stream>>>(bufB, Wl, bl, out);
}

// Round 2
// 579.609 us; speedup vs baseline: 1.2067x; 1.2067x over previous
//
#include <hip/hip_runtime.h>
#include <math.h>

// Problem constants (from reference)
constexpr int N_NODES = 50000;
constexpr int N_EDGES = 800000;
constexpr int TOT_E   = N_EDGES + N_NODES;   // + self loops
constexpr int HCv     = 256;                 // H*C
constexpr int Cv      = 128;                 // per-head channels

// ---------------- CSR build ----------------

__global__ void count_deg_k(const int* __restrict__ ei, int* __restrict__ deg) {
    int e = blockIdx.x * blockDim.x + threadIdx.x;
    if (e >= TOT_E) return;
    int dst = (e < N_EDGES) ? ei[N_EDGES + e] : (e - N_EDGES);
    atomicAdd(&deg[dst], 1);
}

// one-pass offsets: wave-level shuffle prefix-scan of degrees, one atomicAdd
// per wave reserves a contiguous chunk. Row ordering in colv is run-dependent
// but each node's range is contiguous -> output invariant (modulo fp order,
// same as the atomic scatter already was).
__global__ void offsets_k(const int* __restrict__ deg, int* __restrict__ start,
                          int* __restrict__ cursor, int* __restrict__ total) {
    int lane = threadIdx.x & 63;
    int node = blockIdx.x * blockDim.x + threadIdx.x;
    int d = (node < N_NODES) ? deg[node] : 0;
    int pre = d;                       // inclusive scan within wave
#pragma unroll
    for (int off = 1; off < 64; off <<= 1) {
        int v = __shfl_up(pre, off);
        if (lane >= off) pre += v;
    }
    int wtot = __shfl(pre, 63);
    int base = 0;
    if (lane == 63) base = atomicAdd(total, wtot);
    base = __shfl(base, 63);
    int my = base + pre - d;           // exclusive offset
    if (node < N_NODES) { start[node] = my; cursor[node] = my; }
}

__global__ void scatter_k(const int* __restrict__ ei, int* __restrict__ cursor,
                          int* __restrict__ colv) {
    int e = blockIdx.x * blockDim.x + threadIdx.x;
    if (e >= TOT_E) return;
    int srcv, dstv;
    if (e < N_EDGES) { srcv = ei[e]; dstv = ei[N_EDGES + e]; }
    else             { srcv = dstv = e - N_EDGES; }
    int pos = atomicAdd(&cursor[dstv], 1);
    colv[pos] = srcv;
}

// ---------------- fp32 tiled GEMM: C[M x N] = A[M x K] @ B[K x N] ----------------
// BM=BN=64, BK=16, 256 threads, 4x4 per thread. N % 64 == 0, K % 16 == 0 assumed.

__global__ __launch_bounds__(256) void gemm_k(const float* __restrict__ A,
                                              const float* __restrict__ B,
                                              float* __restrict__ C,
                                              int M, int K, int N) {
    __shared__ float As[16][68];   // As[k][row]  (transposed A tile)
    __shared__ float Bs[16][68];   // Bs[k][col]
    const int tid = threadIdx.x;
    const int tx = tid & 15;       // col group (x4)
    const int ty = tid >> 4;       // row group (x4)
    const int row0 = blockIdx.x * 64;
    const int col0 = blockIdx.y * 64;
    float acc[4][4] = {};
    for (int k0 = 0; k0 < K; k0 += 16) {
#pragma unroll
        for (int l = 0; l < 4; ++l) {           // A tile: 64 rows x 16 k
            int idx = tid + l * 256;
            int r = idx >> 4, c = idx & 15;
            int row = row0 + r;
            As[c][r] = (row < M) ? A[row * K + k0 + c] : 0.f;
        }
#pragma unroll
        for (int l = 0; l < 4; ++l) {           // B tile: 16 k x 64 cols
            int idx = tid + l * 256;
            int r = idx >> 6, c = idx & 63;
            Bs[r][c] = B[(k0 + r) * N + col0 + c];
        }
        __syncthreads();
#pragma unroll
        for (int k = 0; k < 16; ++k) {
            float a[4], b[4];
#pragma unroll
            for (int i = 0; i < 4; ++i) a[i] = As[k][ty * 4 + i];
#pragma unroll
            for (int j = 0; j < 4; ++j) b[j] = Bs[k][tx * 4 + j];
#pragma unroll
            for (int i = 0; i < 4; ++i)
#pragma unroll
                for (int j = 0; j < 4; ++j)
                    acc[i][j] += a[i] * b[j];
        }
        __syncthreads();
    }
#pragma unroll
    for (int i = 0; i < 4; ++i) {
        int row = row0 + ty * 4 + i;
        if (row < M) {
            float4 v = make_float4(acc[i][0], acc[i][1], acc[i][2], acc[i][3]);
            *reinterpret_cast<float4*>(&C[row * N + col0 + tx * 4]) = v;
        }
    }
}

// ---------------- attention coefficients: a_s[n,h], a_d[n,h] ----------------
// one wave per (node, head)

__global__ void att_k(const float* __restrict__ h, const float* __restrict__ att_src,
                      const float* __restrict__ att_dst, float* __restrict__ a_s,
                      float* __restrict__ a_d) {
    int lane = threadIdx.x & 63;
    int pair = blockIdx.x * 4 + (threadIdx.x >> 6);
    if (pair >= N_NODES * 2) return;
    int node = pair >> 1, hh = pair & 1;
    const float* hr = h + (size_t)node * HCv + hh * Cv;
    const float* as = att_src + hh * Cv;
    const float* ad = att_dst + hh * Cv;
    float s = 0.f, d = 0.f;
    for (int c = lane; c < Cv; c += 64) {
        float v = hr[c];
        s += v * as[c];
        d += v * ad[c];
    }
#pragma unroll
    for (int off = 32; off; off >>= 1) {
        s += __shfl_down(s, off);
        d += __shfl_down(d, off);
    }
    if (lane == 0) { a_s[pair] = s; a_d[pair] = d; }
}

// ---------------- aggregation: one wave per destination node ----------------
// lane owns channels [lane*4, lane*4+4); head = lane>>5

__device__ __forceinline__ float lrelu(float x) { return x > 0.f ? x : 0.2f * x; }

template <bool TANH>
__global__ void agg_k(const float* __restrict__ h, const float* __restrict__ a_s,
                      const float* __restrict__ a_d, const int* __restrict__ start,
                      const int* __restrict__ deg, const int* __restrict__ colv,
                      const float* __restrict__ bias, float* __restrict__ out) {
    int lane = threadIdx.x & 63;
    int node = blockIdx.x * 4 + (threadIdx.x >> 6);
    if (node >= N_NODES) return;
    int beg = start[node], end = beg + deg[node];
    float ad0 = a_d[node * 2], ad1 = a_d[node * 2 + 1];

    // pass 1: per-head max of leaky-relu logits over incoming edges
    float m0 = -INFINITY, m1 = -INFINITY;
    for (int e = beg + lane; e < end; e += 64) {
        int s = colv[e];
        m0 = fmaxf(m0, lrelu(a_s[s * 2] + ad0));
        m1 = fmaxf(m1, lrelu(a_s[s * 2 + 1] + ad1));
    }
#pragma unroll
    for (int off = 32; off; off >>= 1) {
        m0 = fmaxf(m0, __shfl_xor(m0, off));
        m1 = fmaxf(m1, __shfl_xor(m1, off));
    }
    // pass 2: denominators
    float s0 = 0.f, s1 = 0.f;
    for (int e = beg + lane; e < end; e += 64) {
        int s = colv[e];
        s0 += __expf(lrelu(a_s[s * 2] + ad0) - m0);
        s1 += __expf(lrelu(a_s[s * 2 + 1] + ad1) - m1);
    }
#pragma unroll
    for (int off = 32; off; off >>= 1) {
        s0 += __shfl_xor(s0, off);
        s1 += __shfl_xor(s1, off);
    }
    float inv0 = 1.f / (s0 + 1e-16f), inv1 = 1.f / (s1 + 1e-16f);

    const int head = lane >> 5;
    const float mh  = head ? m1 : m0;
    const float ih  = head ? inv1 : inv0;
    const float adh = head ? ad1 : ad0;
    const int cbase = lane * 4;

    // pass 3: all lanes walk every edge; per-lane float4 channel accumulate
    float acc0 = 0.f, acc1 = 0.f, acc2 = 0.f, acc3 = 0.f;
    for (int e = beg; e < end; ++e) {
        int s = colv[e];
        float l = lrelu(a_s[s * 2 + head] + adh);
        float alpha = __expf(l - mh) * ih;
        const float4 hv = *reinterpret_cast<const float4*>(h + (size_t)s * HCv + cbase);
        acc0 += hv.x * alpha;
        acc1 += hv.y * alpha;
        acc2 += hv.z * alpha;
        acc3 += hv.w * alpha;
    }
    float4 o;
    o.x = acc0 + bias[cbase + 0];
    o.y = acc1 + bias[cbase + 1];
    o.z = acc2 + bias[cbase + 2];
    o.w = acc3 + bias[cbase + 3];
    if (TANH) {
        o.x = tanhf(o.x); o.y = tanhf(o.y); o.z = tanhf(o.z); o.w = tanhf(o.w);
    }
    *reinterpret_cast<float4*>(out + (size_t)node * HCv + cbase) = o;
}

// ---------------- final linear (256 -> 2) + softmax ----------------

__global__ void final_k(const float* __restrict__ h, const float* __restrict__ Wl,
                        const float* __restrict__ bl, float* __restrict__ out) {
    int lane = threadIdx.x & 63;
    int node = blockIdx.x * 4 + (threadIdx.x >> 6);
    if (node >= N_NODES) return;
    const float* hr = h + (size_t)node * HCv;
    float o0 = 0.f, o1 = 0.f;
    for (int k = lane; k < HCv; k += 64) {
        float v = hr[k];
        o0 += v * Wl[k * 2 + 0];
        o1 += v * Wl[k * 2 + 1];
    }
#pragma unroll
    for (int off = 32; off; off >>= 1) {
        o0 += __shfl_down(o0, off);
        o1 += __shfl_down(o1, off);
    }
    if (lane == 0) {
        o0 += bl[0];
        o1 += bl[1];
        float mx = fmaxf(o0, o1);
        float e0 = __expf(o0 - mx), e1 = __expf(o1 - mx);
        float inv = 1.f / (e0 + e1);
        out[node * 2 + 0] = e0 * inv;
        out[node * 2 + 1] = e1 * inv;
    }
}

// ---------------- launch ----------------

extern "C" void kernel_launch(void* const* d_in, const int* in_sizes, int n_in,
                              void* d_out, int out_size, void* d_ws, size_t ws_size,
                              hipStream_t stream) {
    const float* x        = (const float*)d_in[0];
    const int*   ei       = (const int*)d_in[1];
    const float* W0       = (const float*)d_in[2];
    const float* att_src0 = (const float*)d_in[3];
    const float* att_dst0 = (const float*)d_in[4];
    const float* b0       = (const float*)d_in[5];
    const float* W1       = (const float*)d_in[6];
    const float* att_src1 = (const float*)d_in[7];
    const float* att_dst1 = (const float*)d_in[8];
    const float* b1       = (const float*)d_in[9];
    const float* Wl       = (const float*)d_in[10];
    const float* bl       = (const float*)d_in[11];
    float* out = (float*)d_out;

    // workspace layout
    float* bufA = (float*)d_ws;                       // N * 256
    float* bufB = bufA + (size_t)N_NODES * HCv;       // N * 256
    float* a_s  = bufB + (size_t)N_NODES * HCv;       // N * 2
    float* a_d  = a_s + N_NODES * 2;                  // N * 2
    int* deg    = (int*)(a_d + N_NODES * 2);          // N  (+1 for total)
    int* total  = deg + N_NODES;                      // 1
    int* start  = total + 1;                          // N
    int* cursor = start + N_NODES;                    // N
    int* colv   = cursor + N_NODES;                   // E + N

    // ---- CSR build (once per launch; reused by both layers) ----
    hipMemsetAsync(deg, 0, (N_NODES + 1) * sizeof(int), stream);  // deg + total
    int eb = (TOT_E + 255) / 256;
    count_deg_k<<<eb, 256, 0, stream>>>(ei, deg);
    offsets_k<<<(N_NODES + 255) / 256, 256, 0, stream>>>(deg, start, cursor, total);
    scatter_k<<<eb, 256, 0, stream>>>(ei, cursor, colv);

    dim3 ggrid((N_NODES + 63) / 64, HCv / 64);
    int nb4 = (N_NODES * 2 + 3) / 4;   // wave-per-pair blocks
    int nn4 = (N_NODES + 3) / 4;       // wave-per-node blocks

    // ---- layer 0 ----
    gemm_k<<<ggrid, 256, 0, stream>>>(x, W0, bufA, N_NODES, 128, HCv);
    att_k<<<nb4, 256, 0, stream>>>(bufA, att_src0, att_dst0, a_s, a_d);
    agg_k<true><<<nn4, 256, 0, stream>>>(bufA, a_s, a_d, start, deg, colv, b0, bufB);

    // ---- layer 1 ----
    gemm_k<<<ggrid, 256, 0, stream>>>(bufB, W1, bufA, N_NODES, HCv, HCv);
    att_k<<<nb4, 256, 0, stream>>>(bufA, att_src1, att_dst1, a_s, a_d);
    agg_k<false><<<nn4, 256, 0, stream>>>(bufA, a_s, a_d, start, deg, colv, b1, bufB);

    // ---- final linear + softmax ----
    final_k<<<nn4, 256, 0, stream>>>(bufB, Wl, bl, out);
}

// Round 3
// 515.515 us; speedup vs baseline: 1.3567x; 1.1243x over previous
//
#include <hip/hip_runtime.h>
#include <math.h>

// Problem constants (from reference)
constexpr int N_NODES = 50000;
constexpr int N_EDGES = 800000;
constexpr int TOT_E   = N_EDGES + N_NODES;   // + self loops
constexpr int HCv     = 256;                 // H*C
constexpr int Cv      = 128;                 // per-head channels

// ---- bf16 helpers (manual RNE, deterministic) ----
__device__ __forceinline__ unsigned short f2bf(float f) {
    unsigned int u = __float_as_uint(f);
    unsigned int r = (u + 0x7fffu + ((u >> 16) & 1u)) >> 16;
    return (unsigned short)r;
}
__device__ __forceinline__ float bf2f_lo(unsigned int packed) {
    return __uint_as_float(packed << 16);
}
__device__ __forceinline__ float bf2f_hi(unsigned int packed) {
    return __uint_as_float(packed & 0xffff0000u);
}

// ---------------- CSR build ----------------

__global__ void count_deg_k(const int* __restrict__ ei, int* __restrict__ deg) {
    int e = blockIdx.x * blockDim.x + threadIdx.x;
    if (e >= TOT_E) return;
    int dst = (e < N_EDGES) ? ei[N_EDGES + e] : (e - N_EDGES);
    atomicAdd(&deg[dst], 1);
}

// one-pass offsets: wave-level shuffle prefix-scan of degrees, one atomicAdd
// per wave reserves a contiguous chunk.
__global__ void offsets_k(const int* __restrict__ deg, int* __restrict__ start,
                          int* __restrict__ cursor, int* __restrict__ total) {
    int lane = threadIdx.x & 63;
    int node = blockIdx.x * blockDim.x + threadIdx.x;
    int d = (node < N_NODES) ? deg[node] : 0;
    int pre = d;                       // inclusive scan within wave
#pragma unroll
    for (int off = 1; off < 64; off <<= 1) {
        int v = __shfl_up(pre, off);
        if (lane >= off) pre += v;
    }
    int wtot = __shfl(pre, 63);
    int base = 0;
    if (lane == 63) base = atomicAdd(total, wtot);
    base = __shfl(base, 63);
    int my = base + pre - d;           // exclusive offset
    if (node < N_NODES) { start[node] = my; cursor[node] = my; }
}

__global__ void scatter_k(const int* __restrict__ ei, int* __restrict__ cursor,
                          int* __restrict__ colv) {
    int e = blockIdx.x * blockDim.x + threadIdx.x;
    if (e >= TOT_E) return;
    int srcv, dstv;
    if (e < N_EDGES) { srcv = ei[e]; dstv = ei[N_EDGES + e]; }
    else             { srcv = dstv = e - N_EDGES; }
    int pos = atomicAdd(&cursor[dstv], 1);
    colv[pos] = srcv;
}

// ---------------- fp32 tiled GEMM + fused attention epilogue ----------------
// C = A[M x K] @ B[K x 256]; writes bf16 h16 and atomically accumulates
// a_s[row,head] / a_d[row,head] from the fp32 accumulators (attention stays
// fp32-exact; only the gathered messages are bf16-rounded).

__global__ __launch_bounds__(256) void gemm_att_k(const float* __restrict__ A,
                                                  const float* __restrict__ B,
                                                  unsigned short* __restrict__ h16,
                                                  const float* __restrict__ att_src,
                                                  const float* __restrict__ att_dst,
                                                  float* __restrict__ a_s,
                                                  float* __restrict__ a_d,
                                                  int M, int K) {
    __shared__ float As[16][68];   // As[k][row]
    __shared__ float Bs[16][68];   // Bs[k][col]
    const int tid = threadIdx.x;
    const int tx = tid & 15;       // col group (x4)
    const int ty = tid >> 4;       // row group (x4)
    const int row0 = blockIdx.x * 64;
    const int col0 = blockIdx.y * 64;
    float acc[4][4] = {};
    for (int k0 = 0; k0 < K; k0 += 16) {
#pragma unroll
        for (int l = 0; l < 4; ++l) {           // A tile: 64 rows x 16 k
            int idx = tid + l * 256;
            int r = idx >> 4, c = idx & 15;
            int row = row0 + r;
            As[c][r] = (row < M) ? A[(size_t)row * K + k0 + c] : 0.f;
        }
#pragma unroll
        for (int l = 0; l < 4; ++l) {           // B tile: 16 k x 64 cols
            int idx = tid + l * 256;
            int r = idx >> 6, c = idx & 63;
            Bs[r][c] = B[(size_t)(k0 + r) * HCv + col0 + c];
        }
        __syncthreads();
#pragma unroll
        for (int k = 0; k < 16; ++k) {
            float a[4], b[4];
#pragma unroll
            for (int i = 0; i < 4; ++i) a[i] = As[k][ty * 4 + i];
#pragma unroll
            for (int j = 0; j < 4; ++j) b[j] = Bs[k][tx * 4 + j];
#pragma unroll
            for (int i = 0; i < 4; ++i)
#pragma unroll
                for (int j = 0; j < 4; ++j)
                    acc[i][j] += a[i] * b[j];
        }
        __syncthreads();
    }

    // ---- attention partial dots (att_src/att_dst flat [H*C] == indexed by col) ----
    float ps[4] = {}, pd[4] = {};
#pragma unroll
    for (int j = 0; j < 4; ++j) {
        float asv = att_src[col0 + tx * 4 + j];
        float adv = att_dst[col0 + tx * 4 + j];
#pragma unroll
        for (int i = 0; i < 4; ++i) {
            ps[i] += acc[i][j] * asv;
            pd[i] += acc[i][j] * adv;
        }
    }
#pragma unroll
    for (int off = 1; off < 16; off <<= 1) {
#pragma unroll
        for (int i = 0; i < 4; ++i) {
            ps[i] += __shfl_xor(ps[i], off);
            pd[i] += __shfl_xor(pd[i], off);
        }
    }
    const int head = col0 >> 7;
    if (tx == 0) {
#pragma unroll
        for (int i = 0; i < 4; ++i) {
            int row = row0 + ty * 4 + i;
            if (row < M) {
                atomicAdd(&a_s[row * 2 + head], ps[i]);
                atomicAdd(&a_d[row * 2 + head], pd[i]);
            }
        }
    }

    // ---- bf16 store of h ----
#pragma unroll
    for (int i = 0; i < 4; ++i) {
        int row = row0 + ty * 4 + i;
        if (row < M) {
            ushort4 v;
            v.x = f2bf(acc[i][0]);
            v.y = f2bf(acc[i][1]);
            v.z = f2bf(acc[i][2]);
            v.w = f2bf(acc[i][3]);
            *reinterpret_cast<ushort4*>(&h16[(size_t)row * HCv + col0 + tx * 4]) = v;
        }
    }
}

// ---------------- aggregation: one wave per destination node ----------------
// lane owns channels [lane*4, lane*4+4); head = lane>>5. Messages gathered bf16.

__device__ __forceinline__ float lrelu(float x) { return x > 0.f ? x : 0.2f * x; }

template <bool TANH>
__global__ void agg_k(const unsigned short* __restrict__ h16,
                      const float* __restrict__ a_s, const float* __restrict__ a_d,
                      const int* __restrict__ start, const int* __restrict__ deg,
                      const int* __restrict__ colv, const float* __restrict__ bias,
                      float* __restrict__ out) {
    int lane = threadIdx.x & 63;
    int node = blockIdx.x * 4 + (threadIdx.x >> 6);
    if (node >= N_NODES) return;
    int beg = start[node], end = beg + deg[node];
    float ad0 = a_d[node * 2], ad1 = a_d[node * 2 + 1];

    // pass 1: per-head max of leaky-relu logits over incoming edges
    float m0 = -INFINITY, m1 = -INFINITY;
    for (int e = beg + lane; e < end; e += 64) {
        int s = colv[e];
        m0 = fmaxf(m0, lrelu(a_s[s * 2] + ad0));
        m1 = fmaxf(m1, lrelu(a_s[s * 2 + 1] + ad1));
    }
#pragma unroll
    for (int off = 32; off; off >>= 1) {
        m0 = fmaxf(m0, __shfl_xor(m0, off));
        m1 = fmaxf(m1, __shfl_xor(m1, off));
    }
    // pass 2: denominators
    float s0 = 0.f, s1 = 0.f;
    for (int e = beg + lane; e < end; e += 64) {
        int s = colv[e];
        s0 += __expf(lrelu(a_s[s * 2] + ad0) - m0);
        s1 += __expf(lrelu(a_s[s * 2 + 1] + ad1) - m1);
    }
#pragma unroll
    for (int off = 32; off; off >>= 1) {
        s0 += __shfl_xor(s0, off);
        s1 += __shfl_xor(s1, off);
    }
    float inv0 = 1.f / (s0 + 1e-16f), inv1 = 1.f / (s1 + 1e-16f);

    const int head = lane >> 5;
    const float mh  = head ? m1 : m0;
    const float ih  = head ? inv1 : inv0;
    const float adh = head ? ad1 : ad0;
    const int cbase = lane * 4;

    // pass 3: all lanes walk every edge; per-lane 4-channel bf16 gather
    float acc0 = 0.f, acc1 = 0.f, acc2 = 0.f, acc3 = 0.f;
    for (int e = beg; e < end; ++e) {
        int s = colv[e];
        float l = lrelu(a_s[s * 2 + head] + adh);
        float alpha = __expf(l - mh) * ih;
        uint2 hv = *reinterpret_cast<const uint2*>(h16 + (size_t)s * HCv + cbase);
        acc0 = fmaf(bf2f_lo(hv.x), alpha, acc0);
        acc1 = fmaf(bf2f_hi(hv.x), alpha, acc1);
        acc2 = fmaf(bf2f_lo(hv.y), alpha, acc2);
        acc3 = fmaf(bf2f_hi(hv.y), alpha, acc3);
    }
    float4 o;
    o.x = acc0 + bias[cbase + 0];
    o.y = acc1 + bias[cbase + 1];
    o.z = acc2 + bias[cbase + 2];
    o.w = acc3 + bias[cbase + 3];
    if (TANH) {
        o.x = tanhf(o.x); o.y = tanhf(o.y); o.z = tanhf(o.z); o.w = tanhf(o.w);
    }
    *reinterpret_cast<float4*>(out + (size_t)node * HCv + cbase) = o;
}

// ---------------- final linear (256 -> 2) + softmax ----------------

__global__ void final_k(const float* __restrict__ h, const float* __restrict__ Wl,
                        const float* __restrict__ bl, float* __restrict__ out) {
    int lane = threadIdx.x & 63;
    int node = blockIdx.x * 4 + (threadIdx.x >> 6);
    if (node >= N_NODES) return;
    const float* hr = h + (size_t)node * HCv;
    float o0 = 0.f, o1 = 0.f;
    for (int k = lane; k < HCv; k += 64) {
        float v = hr[k];
        o0 += v * Wl[k * 2 + 0];
        o1 += v * Wl[k * 2 + 1];
    }
#pragma unroll
    for (int off = 32; off; off >>= 1) {
        o0 += __shfl_down(o0, off);
        o1 += __shfl_down(o1, off);
    }
    if (lane == 0) {
        o0 += bl[0];
        o1 += bl[1];
        float mx = fmaxf(o0, o1);
        float e0 = __expf(o0 - mx), e1 = __expf(o1 - mx);
        float inv = 1.f / (e0 + e1);
        out[node * 2 + 0] = e0 * inv;
        out[node * 2 + 1] = e1 * inv;
    }
}

// ---------------- launch ----------------

extern "C" void kernel_launch(void* const* d_in, const int* in_sizes, int n_in,
                              void* d_out, int out_size, void* d_ws, size_t ws_size,
                              hipStream_t stream) {
    const float* x        = (const float*)d_in[0];
    const int*   ei       = (const int*)d_in[1];
    const float* W0       = (const float*)d_in[2];
    const float* att_src0 = (const float*)d_in[3];
    const float* att_dst0 = (const float*)d_in[4];
    const float* b0       = (const float*)d_in[5];
    const float* W1       = (const float*)d_in[6];
    const float* att_src1 = (const float*)d_in[7];
    const float* att_dst1 = (const float*)d_in[8];
    const float* b1       = (const float*)d_in[9];
    const float* Wl       = (const float*)d_in[10];
    const float* bl       = (const float*)d_in[11];
    float* out = (float*)d_out;

    // workspace layout
    float* fbuf = (float*)d_ws;                               // N*256 fp32 (agg out / gemm A)
    unsigned short* h16 = (unsigned short*)(fbuf + (size_t)N_NODES * HCv);  // N*256 bf16
    float* a_s  = (float*)(h16 + (size_t)N_NODES * HCv);      // N*2
    float* a_d  = a_s + N_NODES * 2;                          // N*2
    int* deg    = (int*)(a_d + N_NODES * 2);                  // N
    int* total  = deg + N_NODES;                              // 1
    int* start  = total + 1;                                  // N
    int* cursor = start + N_NODES;                            // N
    int* colv   = cursor + N_NODES;                           // E + N

    // ---- CSR build (once per launch; reused by both layers) ----
    hipMemsetAsync(deg, 0, (N_NODES + 1) * sizeof(int), stream);  // deg + total
    int eb = (TOT_E + 255) / 256;
    count_deg_k<<<eb, 256, 0, stream>>>(ei, deg);
    offsets_k<<<(N_NODES + 255) / 256, 256, 0, stream>>>(deg, start, cursor, total);
    scatter_k<<<eb, 256, 0, stream>>>(ei, cursor, colv);

    dim3 ggrid((N_NODES + 63) / 64, HCv / 64);
    int nn4 = (N_NODES + 3) / 4;       // wave-per-node blocks

    // ---- layer 0 ----
    hipMemsetAsync(a_s, 0, (size_t)N_NODES * 4 * sizeof(float), stream);  // a_s + a_d
    gemm_att_k<<<ggrid, 256, 0, stream>>>(x, W0, h16, att_src0, att_dst0,
                                          a_s, a_d, N_NODES, 128);
    agg_k<true><<<nn4, 256, 0, stream>>>(h16, a_s, a_d, start, deg, colv, b0, fbuf);

    // ---- layer 1 ----
    hipMemsetAsync(a_s, 0, (size_t)N_NODES * 4 * sizeof(float), stream);
    gemm_att_k<<<ggrid, 256, 0, stream>>>(fbuf, W1, h16, att_src1, att_dst1,
                                          a_s, a_d, N_NODES, HCv);
    agg_k<false><<<nn4, 256, 0, stream>>>(h16, a_s, a_d, start, deg, colv, b1, fbuf);

    // ---- final linear + softmax ----
    final_k<<<nn4, 256, 0, stream>>>(fbuf, Wl, bl, out);
}

// Round 4
// 451.932 us; speedup vs baseline: 1.5476x; 1.1407x over previous
//
#include <hip/hip_runtime.h>
#include <math.h>

// Problem constants (from reference)
constexpr int N_NODES = 50000;
constexpr int N_EDGES = 800000;
constexpr int TOT_E   = N_EDGES + N_NODES;   // + self loops
constexpr int HCv     = 256;                 // H*C
constexpr int Cv      = 128;                 // per-head channels
constexpr int MAXD    = 256;                 // LDS logit-cache capacity per wave

// ---- bf16 helpers (manual RNE, deterministic) ----
__device__ __forceinline__ unsigned short f2bf(float f) {
    unsigned int u = __float_as_uint(f);
    unsigned int r = (u + 0x7fffu + ((u >> 16) & 1u)) >> 16;
    return (unsigned short)r;
}
__device__ __forceinline__ float bf2f_lo(unsigned int packed) {
    return __uint_as_float(packed << 16);
}
__device__ __forceinline__ float bf2f_hi(unsigned int packed) {
    return __uint_as_float(packed & 0xffff0000u);
}

// ---------------- CSR build ----------------

__global__ void count_deg_k(const int* __restrict__ ei, int* __restrict__ deg) {
    int e = blockIdx.x * blockDim.x + threadIdx.x;
    if (e >= TOT_E) return;
    int dst = (e < N_EDGES) ? ei[N_EDGES + e] : (e - N_EDGES);
    atomicAdd(&deg[dst], 1);
}

__global__ void offsets_k(const int* __restrict__ deg, int* __restrict__ start,
                          int* __restrict__ cursor, int* __restrict__ total) {
    int lane = threadIdx.x & 63;
    int node = blockIdx.x * blockDim.x + threadIdx.x;
    int d = (node < N_NODES) ? deg[node] : 0;
    int pre = d;                       // inclusive scan within wave
#pragma unroll
    for (int off = 1; off < 64; off <<= 1) {
        int v = __shfl_up(pre, off);
        if (lane >= off) pre += v;
    }
    int wtot = __shfl(pre, 63);
    int base = 0;
    if (lane == 63) base = atomicAdd(total, wtot);
    base = __shfl(base, 63);
    int my = base + pre - d;           // exclusive offset
    if (node < N_NODES) { start[node] = my; cursor[node] = my; }
}

__global__ void scatter_k(const int* __restrict__ ei, int* __restrict__ cursor,
                          int* __restrict__ colv) {
    int e = blockIdx.x * blockDim.x + threadIdx.x;
    if (e >= TOT_E) return;
    int srcv, dstv;
    if (e < N_EDGES) { srcv = ei[e]; dstv = ei[N_EDGES + e]; }
    else             { srcv = dstv = e - N_EDGES; }
    int pos = atomicAdd(&cursor[dstv], 1);
    colv[pos] = srcv;
}

// ---------------- fp32 tiled GEMM + fused attention epilogue ----------------

__global__ __launch_bounds__(256) void gemm_att_k(const float* __restrict__ A,
                                                  const float* __restrict__ B,
                                                  unsigned short* __restrict__ h16,
                                                  const float* __restrict__ att_src,
                                                  const float* __restrict__ att_dst,
                                                  float* __restrict__ a_s,
                                                  float* __restrict__ a_d,
                                                  int M, int K) {
    __shared__ float As[16][68];   // As[k][row]
    __shared__ float Bs[16][68];   // Bs[k][col]
    const int tid = threadIdx.x;
    const int tx = tid & 15;       // col group (x4)
    const int ty = tid >> 4;       // row group (x4)
    const int row0 = blockIdx.x * 64;
    const int col0 = blockIdx.y * 64;
    float acc[4][4] = {};
    for (int k0 = 0; k0 < K; k0 += 16) {
#pragma unroll
        for (int l = 0; l < 4; ++l) {           // A tile: 64 rows x 16 k
            int idx = tid + l * 256;
            int r = idx >> 4, c = idx & 15;
            int row = row0 + r;
            As[c][r] = (row < M) ? A[(size_t)row * K + k0 + c] : 0.f;
        }
#pragma unroll
        for (int l = 0; l < 4; ++l) {           // B tile: 16 k x 64 cols
            int idx = tid + l * 256;
            int r = idx >> 6, c = idx & 63;
            Bs[r][c] = B[(size_t)(k0 + r) * HCv + col0 + c];
        }
        __syncthreads();
#pragma unroll
        for (int k = 0; k < 16; ++k) {
            float a[4], b[4];
#pragma unroll
            for (int i = 0; i < 4; ++i) a[i] = As[k][ty * 4 + i];
#pragma unroll
            for (int j = 0; j < 4; ++j) b[j] = Bs[k][tx * 4 + j];
#pragma unroll
            for (int i = 0; i < 4; ++i)
#pragma unroll
                for (int j = 0; j < 4; ++j)
                    acc[i][j] += a[i] * b[j];
        }
        __syncthreads();
    }

    // ---- attention partial dots ----
    float ps[4] = {}, pd[4] = {};
#pragma unroll
    for (int j = 0; j < 4; ++j) {
        float asv = att_src[col0 + tx * 4 + j];
        float adv = att_dst[col0 + tx * 4 + j];
#pragma unroll
        for (int i = 0; i < 4; ++i) {
            ps[i] += acc[i][j] * asv;
            pd[i] += acc[i][j] * adv;
        }
    }
#pragma unroll
    for (int off = 1; off < 16; off <<= 1) {
#pragma unroll
        for (int i = 0; i < 4; ++i) {
            ps[i] += __shfl_xor(ps[i], off);
            pd[i] += __shfl_xor(pd[i], off);
        }
    }
    const int head = col0 >> 7;
    if (tx == 0) {
#pragma unroll
        for (int i = 0; i < 4; ++i) {
            int row = row0 + ty * 4 + i;
            if (row < M) {
                atomicAdd(&a_s[row * 2 + head], ps[i]);
                atomicAdd(&a_d[row * 2 + head], pd[i]);
            }
        }
    }

    // ---- bf16 store of h ----
#pragma unroll
    for (int i = 0; i < 4; ++i) {
        int row = row0 + ty * 4 + i;
        if (row < M) {
            ushort4 v;
            v.x = f2bf(acc[i][0]);
            v.y = f2bf(acc[i][1]);
            v.z = f2bf(acc[i][2]);
            v.w = f2bf(acc[i][3]);
            *reinterpret_cast<ushort4*>(&h16[(size_t)row * HCv + col0 + tx * 4]) = v;
        }
    }
}

// ---------------- aggregation: one wave per destination node ----------------
// Fast path (deg <= MAXD): logits computed once into per-wave LDS cache; all
// exp in the parallel phase; pass 3 does 2 edges/iter (half-wave x uint4).

__device__ __forceinline__ float lrelu(float x) { return x > 0.f ? x : 0.2f * x; }

template <bool TANH>
__global__ __launch_bounds__(256) void agg_k(const unsigned short* __restrict__ h16,
                      const float* __restrict__ a_s, const float* __restrict__ a_d,
                      const int* __restrict__ start, const int* __restrict__ deg,
                      const int* __restrict__ colv, const float* __restrict__ bias,
                      float* __restrict__ out) {
    __shared__ float lexp[4][2][MAXD];
    const int lane = threadIdx.x & 63;
    const int wslot = threadIdx.x >> 6;
    const int node = blockIdx.x * 4 + wslot;
    if (node >= N_NODES) return;
    const int beg = start[node];
    const int degv = deg[node];
    const int end = beg + degv;
    const float ad0 = a_d[node * 2], ad1 = a_d[node * 2 + 1];
    const int* __restrict__ col = colv + beg;

    float inv0, inv1, m0, m1;

    if (degv <= MAXD) {
        // ---- pass 1: logits -> LDS, per-head max ----
        m0 = -INFINITY; m1 = -INFINITY;
        for (int j = lane; j < degv; j += 64) {
            int s = col[j];
            float2 av = *reinterpret_cast<const float2*>(a_s + s * 2);
            float l0 = lrelu(av.x + ad0);
            float l1 = lrelu(av.y + ad1);
            lexp[wslot][0][j] = l0;
            lexp[wslot][1][j] = l1;
            m0 = fmaxf(m0, l0);
            m1 = fmaxf(m1, l1);
        }
#pragma unroll
        for (int off = 32; off; off >>= 1) {
            m0 = fmaxf(m0, __shfl_xor(m0, off));
            m1 = fmaxf(m1, __shfl_xor(m1, off));
        }
        // ---- pass 2: exp (LDS-only), sums ----
        float s0 = 0.f, s1 = 0.f;
        for (int j = lane; j < degv; j += 64) {
            float e0 = __expf(lexp[wslot][0][j] - m0);
            float e1 = __expf(lexp[wslot][1][j] - m1);
            lexp[wslot][0][j] = e0;
            lexp[wslot][1][j] = e1;
            s0 += e0;
            s1 += e1;
        }
#pragma unroll
        for (int off = 32; off; off >>= 1) {
            s0 += __shfl_xor(s0, off);
            s1 += __shfl_xor(s1, off);
        }
        inv0 = 1.f / (s0 + 1e-16f);
        inv1 = 1.f / (s1 + 1e-16f);

        // ---- pass 3: 2 edges/iter; lane = (half, w); w owns 8 channels ----
        const int half = lane >> 5;
        const int w = lane & 31;
        const int hh = w >> 4;                 // head of my channels
        const float invh = hh ? inv1 : inv0;
        float acc[8] = {};
        const int iters = (degv + 1) >> 1;
        for (int i = 0; i < iters; ++i) {
            int j = 2 * i + half;
            if (j < degv) {
                int s = col[j];
                float alpha = lexp[wslot][hh][j] * invh;
                uint4 hv = *reinterpret_cast<const uint4*>(h16 + (size_t)s * HCv + w * 8);
                acc[0] = fmaf(bf2f_lo(hv.x), alpha, acc[0]);
                acc[1] = fmaf(bf2f_hi(hv.x), alpha, acc[1]);
                acc[2] = fmaf(bf2f_lo(hv.y), alpha, acc[2]);
                acc[3] = fmaf(bf2f_hi(hv.y), alpha, acc[3]);
                acc[4] = fmaf(bf2f_lo(hv.z), alpha, acc[4]);
                acc[5] = fmaf(bf2f_hi(hv.z), alpha, acc[5]);
                acc[6] = fmaf(bf2f_lo(hv.w), alpha, acc[6]);
                acc[7] = fmaf(bf2f_hi(hv.w), alpha, acc[7]);
            }
        }
#pragma unroll
        for (int c = 0; c < 8; ++c) acc[c] += __shfl_xor(acc[c], 32);
        // half 0 writes channels w*8..+3, half 1 writes w*8+4..+7
        const int cb = w * 8 + half * 4;
        float4 o;
        o.x = acc[half * 4 + 0] + bias[cb + 0];
        o.y = acc[half * 4 + 1] + bias[cb + 1];
        o.z = acc[half * 4 + 2] + bias[cb + 2];
        o.w = acc[half * 4 + 3] + bias[cb + 3];
        if (TANH) {
            o.x = tanhf(o.x); o.y = tanhf(o.y); o.z = tanhf(o.z); o.w = tanhf(o.w);
        }
        *reinterpret_cast<float4*>(out + (size_t)node * HCv + cb) = o;
    } else {
        // ---- fallback: original 3-pass recompute path (deg > MAXD) ----
        m0 = -INFINITY; m1 = -INFINITY;
        for (int e = beg + lane; e < end; e += 64) {
            int s = colv[e];
            m0 = fmaxf(m0, lrelu(a_s[s * 2] + ad0));
            m1 = fmaxf(m1, lrelu(a_s[s * 2 + 1] + ad1));
        }
#pragma unroll
        for (int off = 32; off; off >>= 1) {
            m0 = fmaxf(m0, __shfl_xor(m0, off));
            m1 = fmaxf(m1, __shfl_xor(m1, off));
        }
        float s0 = 0.f, s1 = 0.f;
        for (int e = beg + lane; e < end; e += 64) {
            int s = colv[e];
            s0 += __expf(lrelu(a_s[s * 2] + ad0) - m0);
            s1 += __expf(lrelu(a_s[s * 2 + 1] + ad1) - m1);
        }
#pragma unroll
        for (int off = 32; off; off >>= 1) {
            s0 += __shfl_xor(s0, off);
            s1 += __shfl_xor(s1, off);
        }
        inv0 = 1.f / (s0 + 1e-16f);
        inv1 = 1.f / (s1 + 1e-16f);
        const int head = lane >> 5;
        const float mh  = head ? m1 : m0;
        const float ih  = head ? inv1 : inv0;
        const float adh = head ? ad1 : ad0;
        const int cbase = lane * 4;
        float acc0 = 0.f, acc1 = 0.f, acc2 = 0.f, acc3 = 0.f;
        for (int e = beg; e < end; ++e) {
            int s = colv[e];
            float l = lrelu(a_s[s * 2 + head] + adh);
            float alpha = __expf(l - mh) * ih;
            uint2 hv = *reinterpret_cast<const uint2*>(h16 + (size_t)s * HCv + cbase);
            acc0 = fmaf(bf2f_lo(hv.x), alpha, acc0);
            acc1 = fmaf(bf2f_hi(hv.x), alpha, acc1);
            acc2 = fmaf(bf2f_lo(hv.y), alpha, acc2);
            acc3 = fmaf(bf2f_hi(hv.y), alpha, acc3);
        }
        float4 o;
        o.x = acc0 + bias[cbase + 0];
        o.y = acc1 + bias[cbase + 1];
        o.z = acc2 + bias[cbase + 2];
        o.w = acc3 + bias[cbase + 3];
        if (TANH) {
            o.x = tanhf(o.x); o.y = tanhf(o.y); o.z = tanhf(o.z); o.w = tanhf(o.w);
        }
        *reinterpret_cast<float4*>(out + (size_t)node * HCv + cbase) = o;
    }
}

// ---------------- final linear (256 -> 2) + softmax ----------------

__global__ void final_k(const float* __restrict__ h, const float* __restrict__ Wl,
                        const float* __restrict__ bl, float* __restrict__ out) {
    int lane = threadIdx.x & 63;
    int node = blockIdx.x * 4 + (threadIdx.x >> 6);
    if (node >= N_NODES) return;
    const float* hr = h + (size_t)node * HCv;
    float o0 = 0.f, o1 = 0.f;
    for (int k = lane; k < HCv; k += 64) {
        float v = hr[k];
        o0 += v * Wl[k * 2 + 0];
        o1 += v * Wl[k * 2 + 1];
    }
#pragma unroll
    for (int off = 32; off; off >>= 1) {
        o0 += __shfl_down(o0, off);
        o1 += __shfl_down(o1, off);
    }
    if (lane == 0) {
        o0 += bl[0];
        o1 += bl[1];
        float mx = fmaxf(o0, o1);
        float e0 = __expf(o0 - mx), e1 = __expf(o1 - mx);
        float inv = 1.f / (e0 + e1);
        out[node * 2 + 0] = e0 * inv;
        out[node * 2 + 1] = e1 * inv;
    }
}

// ---------------- launch ----------------

extern "C" void kernel_launch(void* const* d_in, const int* in_sizes, int n_in,
                              void* d_out, int out_size, void* d_ws, size_t ws_size,
                              hipStream_t stream) {
    const float* x        = (const float*)d_in[0];
    const int*   ei       = (const int*)d_in[1];
    const float* W0       = (const float*)d_in[2];
    const float* att_src0 = (const float*)d_in[3];
    const float* att_dst0 = (const float*)d_in[4];
    const float* b0       = (const float*)d_in[5];
    const float* W1       = (const float*)d_in[6];
    const float* att_src1 = (const float*)d_in[7];
    const float* att_dst1 = (const float*)d_in[8];
    const float* b1       = (const float*)d_in[9];
    const float* Wl       = (const float*)d_in[10];
    const float* bl       = (const float*)d_in[11];
    float* out = (float*)d_out;

    // workspace layout
    float* fbuf = (float*)d_ws;                               // N*256 fp32
    unsigned short* h16 = (unsigned short*)(fbuf + (size_t)N_NODES * HCv);  // N*256 bf16
    float* a_s  = (float*)(h16 + (size_t)N_NODES * HCv);      // N*2
    float* a_d  = a_s + N_NODES * 2;                          // N*2
    int* deg    = (int*)(a_d + N_NODES * 2);                  // N
    int* total  = deg + N_NODES;                              // 1
    int* start  = total + 1;                                  // N
    int* cursor = start + N_NODES;                            // N
    int* colv   = cursor + N_NODES;                           // E + N

    // ---- CSR build ----
    hipMemsetAsync(deg, 0, (N_NODES + 1) * sizeof(int), stream);
    int eb = (TOT_E + 255) / 256;
    count_deg_k<<<eb, 256, 0, stream>>>(ei, deg);
    offsets_k<<<(N_NODES + 255) / 256, 256, 0, stream>>>(deg, start, cursor, total);
    scatter_k<<<eb, 256, 0, stream>>>(ei, cursor, colv);

    dim3 ggrid((N_NODES + 63) / 64, HCv / 64);
    int nn4 = (N_NODES + 3) / 4;

    // ---- layer 0 ----
    hipMemsetAsync(a_s, 0, (size_t)N_NODES * 4 * sizeof(float), stream);
    gemm_att_k<<<ggrid, 256, 0, stream>>>(x, W0, h16, att_src0, att_dst0,
                                          a_s, a_d, N_NODES, 128);
    agg_k<true><<<nn4, 256, 0, stream>>>(h16, a_s, a_d, start, deg, colv, b0, fbuf);

    // ---- layer 1 ----
    hipMemsetAsync(a_s, 0, (size_t)N_NODES * 4 * sizeof(float), stream);
    gemm_att_k<<<ggrid, 256, 0, stream>>>(fbuf, W1, h16, att_src1, att_dst1,
                                          a_s, a_d, N_NODES, HCv);
    agg_k<false><<<nn4, 256, 0, stream>>>(h16, a_s, a_d, start, deg, colv, b1, fbuf);

    // ---- final linear + softmax ----
    final_k<<<nn4, 256, 0, stream>>>(fbuf, Wl, bl, out);
}

// Round 5
// 357.200 us; speedup vs baseline: 1.9581x; 1.2652x over previous
//
#include <hip/hip_runtime.h>
#include <math.h>

// Problem constants (from reference)
constexpr int N_NODES = 50000;
constexpr int N_EDGES = 800000;
constexpr int TOT_E   = N_EDGES + N_NODES;   // + self loops
constexpr int HCv     = 256;                 // H*C
constexpr int MAXD    = 256;                 // LDS logit-cache capacity per wave

typedef __attribute__((ext_vector_type(8))) short bf16x8;
typedef __attribute__((ext_vector_type(4))) float f32x4;

// ---- bf16 helpers (manual RNE, deterministic) ----
__device__ __forceinline__ unsigned short f2bf(float f) {
    unsigned int u = __float_as_uint(f);
    unsigned int r = (u + 0x7fffu + ((u >> 16) & 1u)) >> 16;
    return (unsigned short)r;
}
__device__ __forceinline__ float bf2f_lo(unsigned int packed) {
    return __uint_as_float(packed << 16);
}
__device__ __forceinline__ float bf2f_hi(unsigned int packed) {
    return __uint_as_float(packed & 0xffff0000u);
}

// ---------------- prep: fp32 -> bf16 convert / weight transpose ----------------

__global__ void cvt_bf16_k(const float* __restrict__ in, unsigned short* __restrict__ out,
                           int n4) {
    int i = blockIdx.x * blockDim.x + threadIdx.x;
    if (i >= n4) return;
    float4 v = *reinterpret_cast<const float4*>(in + (size_t)i * 4);
    ushort4 o;
    o.x = f2bf(v.x); o.y = f2bf(v.y); o.z = f2bf(v.z); o.w = f2bf(v.w);
    *reinterpret_cast<ushort4*>(out + (size_t)i * 4) = o;
}

// WT[n][k] = bf16(W[k][n]);  W is [K][256]
__global__ void wt_k(const float* __restrict__ W, unsigned short* __restrict__ WT, int K) {
    int idx = blockIdx.x * 256 + threadIdx.x;
    if (idx >= K * 256) return;
    int k = idx >> 8, n = idx & 255;
    WT[(size_t)n * K + k] = f2bf(W[idx]);
}

// ---------------- CSR build ----------------

__global__ void count_deg_k(const int* __restrict__ ei, int* __restrict__ deg) {
    int e = blockIdx.x * blockDim.x + threadIdx.x;
    if (e >= TOT_E) return;
    int dst = (e < N_EDGES) ? ei[N_EDGES + e] : (e - N_EDGES);
    atomicAdd(&deg[dst], 1);
}

__global__ void offsets_k(const int* __restrict__ deg, int* __restrict__ start,
                          int* __restrict__ cursor, int* __restrict__ total) {
    int lane = threadIdx.x & 63;
    int node = blockIdx.x * blockDim.x + threadIdx.x;
    int d = (node < N_NODES) ? deg[node] : 0;
    int pre = d;
#pragma unroll
    for (int off = 1; off < 64; off <<= 1) {
        int v = __shfl_up(pre, off);
        if (lane >= off) pre += v;
    }
    int wtot = __shfl(pre, 63);
    int base = 0;
    if (lane == 63) base = atomicAdd(total, wtot);
    base = __shfl(base, 63);
    int my = base + pre - d;
    if (node < N_NODES) { start[node] = my; cursor[node] = my; }
}

__global__ void scatter_k(const int* __restrict__ ei, int* __restrict__ cursor,
                          int* __restrict__ colv) {
    int e = blockIdx.x * blockDim.x + threadIdx.x;
    if (e >= TOT_E) return;
    int srcv, dstv;
    if (e < N_EDGES) { srcv = ei[e]; dstv = ei[N_EDGES + e]; }
    else             { srcv = dstv = e - N_EDGES; }
    int pos = atomicAdd(&cursor[dstv], 1);
    colv[pos] = srcv;
}

// ---------------- MFMA bf16 GEMM + fused attention epilogue ----------------
// C = A[M x K]_bf16 @ W[K x 256]_bf16 via WT[n][k]. Block: 128 rows x 64 cols,
// 4 waves (each 32x64 = acc[2][4] of 16x16 frags). No LDS, no barriers: A and
// WT fragment loads are 16B-contiguous per lane (frag layout: m/n = lane&15,
// k = (lane>>4)*8 + e; D: col = lane&15, row = (lane>>4)*4 + reg).

template <int K>
__global__ __launch_bounds__(256) void mfma_gemm_att_k(
        const unsigned short* __restrict__ A,   // [M][K] bf16
        const unsigned short* __restrict__ BT,  // [256][K] bf16 (W transposed)
        unsigned short* __restrict__ h16,       // [M][256] bf16 out
        const float* __restrict__ att_src, const float* __restrict__ att_dst,
        float* __restrict__ a_s, float* __restrict__ a_d, int M) {
    const int lane = threadIdx.x & 63;
    const int wv = threadIdx.x >> 6;
    const int lm = lane & 15;
    const int g8 = (lane >> 4) * 8;
    const int row0 = blockIdx.y * 128 + wv * 32;
    const int n0 = blockIdx.x * 64;

    int ra0 = row0 + lm;       if (ra0 >= M) ra0 = M - 1;
    int ra1 = row0 + 16 + lm;  if (ra1 >= M) ra1 = M - 1;
    const unsigned short* pa0 = A + (size_t)ra0 * K + g8;
    const unsigned short* pa1 = A + (size_t)ra1 * K + g8;
    const unsigned short* pb  = BT + (size_t)(n0 + lm) * K + g8;

    f32x4 acc[2][4] = {};
#pragma unroll
    for (int kt = 0; kt < K; kt += 32) {
        bf16x8 a0 = *reinterpret_cast<const bf16x8*>(pa0 + kt);
        bf16x8 a1 = *reinterpret_cast<const bf16x8*>(pa1 + kt);
        bf16x8 b0 = *reinterpret_cast<const bf16x8*>(pb + kt);
        bf16x8 b1 = *reinterpret_cast<const bf16x8*>(pb + 16 * K + kt);
        bf16x8 b2 = *reinterpret_cast<const bf16x8*>(pb + 32 * K + kt);
        bf16x8 b3 = *reinterpret_cast<const bf16x8*>(pb + 48 * K + kt);
        acc[0][0] = __builtin_amdgcn_mfma_f32_16x16x32_bf16(a0, b0, acc[0][0], 0, 0, 0);
        acc[0][1] = __builtin_amdgcn_mfma_f32_16x16x32_bf16(a0, b1, acc[0][1], 0, 0, 0);
        acc[0][2] = __builtin_amdgcn_mfma_f32_16x16x32_bf16(a0, b2, acc[0][2], 0, 0, 0);
        acc[0][3] = __builtin_amdgcn_mfma_f32_16x16x32_bf16(a0, b3, acc[0][3], 0, 0, 0);
        acc[1][0] = __builtin_amdgcn_mfma_f32_16x16x32_bf16(a1, b0, acc[1][0], 0, 0, 0);
        acc[1][1] = __builtin_amdgcn_mfma_f32_16x16x32_bf16(a1, b1, acc[1][1], 0, 0, 0);
        acc[1][2] = __builtin_amdgcn_mfma_f32_16x16x32_bf16(a1, b2, acc[1][2], 0, 0, 0);
        acc[1][3] = __builtin_amdgcn_mfma_f32_16x16x32_bf16(a1, b3, acc[1][3], 0, 0, 0);
    }

    // att vectors for my 4 columns (flat [H*C] indexed by col)
    float as_c[4], ad_c[4];
#pragma unroll
    for (int j = 0; j < 4; ++j) {
        int c = n0 + j * 16 + lm;
        as_c[j] = att_src[c];
        ad_c[j] = att_dst[c];
    }
    const int head = n0 >> 7;

#pragma unroll
    for (int i = 0; i < 2; ++i) {
        float ps[4] = {}, pd[4] = {};
#pragma unroll
        for (int j = 0; j < 4; ++j)
#pragma unroll
            for (int r = 0; r < 4; ++r) {
                ps[r] += acc[i][j][r] * as_c[j];
                pd[r] += acc[i][j][r] * ad_c[j];
            }
#pragma unroll
        for (int off = 1; off < 16; off <<= 1)
#pragma unroll
            for (int r = 0; r < 4; ++r) {
                ps[r] += __shfl_xor(ps[r], off);
                pd[r] += __shfl_xor(pd[r], off);
            }
        if (lm == 0) {
            int rb = row0 + i * 16 + (lane >> 4) * 4;
#pragma unroll
            for (int r = 0; r < 4; ++r) {
                if (rb + r < M) {
                    atomicAdd(&a_s[(rb + r) * 2 + head], ps[r]);
                    atomicAdd(&a_d[(rb + r) * 2 + head], pd[r]);
                }
            }
        }
        // bf16 store of h (col = lane&15, row = (lane>>4)*4 + r)
#pragma unroll
        for (int j = 0; j < 4; ++j)
#pragma unroll
            for (int r = 0; r < 4; ++r) {
                int row = row0 + i * 16 + (lane >> 4) * 4 + r;
                if (row < M)
                    h16[(size_t)row * HCv + n0 + j * 16 + lm] = f2bf(acc[i][j][r]);
            }
    }
}

// ---------------- aggregation: one wave per destination node ----------------

__device__ __forceinline__ float lrelu(float x) { return x > 0.f ? x : 0.2f * x; }

template <bool TANH, bool OB16>
__global__ __launch_bounds__(256) void agg_k(const unsigned short* __restrict__ h16,
                      const float* __restrict__ a_s, const float* __restrict__ a_d,
                      const int* __restrict__ start, const int* __restrict__ deg,
                      const int* __restrict__ colv, const float* __restrict__ bias,
                      float* __restrict__ outf, unsigned short* __restrict__ out16) {
    __shared__ float lexp[4][2][MAXD];
    const int lane = threadIdx.x & 63;
    const int wslot = threadIdx.x >> 6;
    const int node = blockIdx.x * 4 + wslot;
    if (node >= N_NODES) return;
    const int beg = start[node];
    const int degv = deg[node];
    const int end = beg + degv;
    const float ad0 = a_d[node * 2], ad1 = a_d[node * 2 + 1];
    const int* __restrict__ col = colv + beg;

    if (degv <= MAXD) {
        float m0 = -INFINITY, m1 = -INFINITY;
        for (int j = lane; j < degv; j += 64) {
            int s = col[j];
            float2 av = *reinterpret_cast<const float2*>(a_s + s * 2);
            float l0 = lrelu(av.x + ad0);
            float l1 = lrelu(av.y + ad1);
            lexp[wslot][0][j] = l0;
            lexp[wslot][1][j] = l1;
            m0 = fmaxf(m0, l0);
            m1 = fmaxf(m1, l1);
        }
#pragma unroll
        for (int off = 32; off; off >>= 1) {
            m0 = fmaxf(m0, __shfl_xor(m0, off));
            m1 = fmaxf(m1, __shfl_xor(m1, off));
        }
        float s0 = 0.f, s1 = 0.f;
        for (int j = lane; j < degv; j += 64) {
            float e0 = __expf(lexp[wslot][0][j] - m0);
            float e1 = __expf(lexp[wslot][1][j] - m1);
            lexp[wslot][0][j] = e0;
            lexp[wslot][1][j] = e1;
            s0 += e0;
            s1 += e1;
        }
#pragma unroll
        for (int off = 32; off; off >>= 1) {
            s0 += __shfl_xor(s0, off);
            s1 += __shfl_xor(s1, off);
        }
        float inv0 = 1.f / (s0 + 1e-16f);
        float inv1 = 1.f / (s1 + 1e-16f);

        const int half = lane >> 5;
        const int w = lane & 31;
        const int hh = w >> 4;
        const float invh = hh ? inv1 : inv0;
        float acc[8] = {};
        const int iters = (degv + 1) >> 1;
        for (int i = 0; i < iters; ++i) {
            int j = 2 * i + half;
            if (j < degv) {
                int s = col[j];
                float alpha = lexp[wslot][hh][j] * invh;
                uint4 hv = *reinterpret_cast<const uint4*>(h16 + (size_t)s * HCv + w * 8);
                acc[0] = fmaf(bf2f_lo(hv.x), alpha, acc[0]);
                acc[1] = fmaf(bf2f_hi(hv.x), alpha, acc[1]);
                acc[2] = fmaf(bf2f_lo(hv.y), alpha, acc[2]);
                acc[3] = fmaf(bf2f_hi(hv.y), alpha, acc[3]);
                acc[4] = fmaf(bf2f_lo(hv.z), alpha, acc[4]);
                acc[5] = fmaf(bf2f_hi(hv.z), alpha, acc[5]);
                acc[6] = fmaf(bf2f_lo(hv.w), alpha, acc[6]);
                acc[7] = fmaf(bf2f_hi(hv.w), alpha, acc[7]);
            }
        }
#pragma unroll
        for (int c = 0; c < 8; ++c) acc[c] += __shfl_xor(acc[c], 32);
        const int cb = w * 8 + half * 4;
        float4 o;
        o.x = acc[half * 4 + 0] + bias[cb + 0];
        o.y = acc[half * 4 + 1] + bias[cb + 1];
        o.z = acc[half * 4 + 2] + bias[cb + 2];
        o.w = acc[half * 4 + 3] + bias[cb + 3];
        if (TANH) {
            o.x = tanhf(o.x); o.y = tanhf(o.y); o.z = tanhf(o.z); o.w = tanhf(o.w);
        }
        if (OB16) {
            ushort4 v;
            v.x = f2bf(o.x); v.y = f2bf(o.y); v.z = f2bf(o.z); v.w = f2bf(o.w);
            *reinterpret_cast<ushort4*>(out16 + (size_t)node * HCv + cb) = v;
        } else {
            *reinterpret_cast<float4*>(outf + (size_t)node * HCv + cb) = o;
        }
    } else {
        // fallback: 3-pass recompute path (deg > MAXD)
        float m0 = -INFINITY, m1 = -INFINITY;
        for (int e = beg + lane; e < end; e += 64) {
            int s = colv[e];
            m0 = fmaxf(m0, lrelu(a_s[s * 2] + ad0));
            m1 = fmaxf(m1, lrelu(a_s[s * 2 + 1] + ad1));
        }
#pragma unroll
        for (int off = 32; off; off >>= 1) {
            m0 = fmaxf(m0, __shfl_xor(m0, off));
            m1 = fmaxf(m1, __shfl_xor(m1, off));
        }
        float s0 = 0.f, s1 = 0.f;
        for (int e = beg + lane; e < end; e += 64) {
            int s = colv[e];
            s0 += __expf(lrelu(a_s[s * 2] + ad0) - m0);
            s1 += __expf(lrelu(a_s[s * 2 + 1] + ad1) - m1);
        }
#pragma unroll
        for (int off = 32; off; off >>= 1) {
            s0 += __shfl_xor(s0, off);
            s1 += __shfl_xor(s1, off);
        }
        float inv0 = 1.f / (s0 + 1e-16f);
        float inv1 = 1.f / (s1 + 1e-16f);
        const int head = lane >> 5;
        const float mh  = head ? m1 : m0;
        const float ih  = head ? inv1 : inv0;
        const float adh = head ? ad1 : ad0;
        const int cbase = lane * 4;
        float acc0 = 0.f, acc1 = 0.f, acc2 = 0.f, acc3 = 0.f;
        for (int e = beg; e < end; ++e) {
            int s = colv[e];
            float l = lrelu(a_s[s * 2 + head] + adh);
            float alpha = __expf(l - mh) * ih;
            uint2 hv = *reinterpret_cast<const uint2*>(h16 + (size_t)s * HCv + cbase);
            acc0 = fmaf(bf2f_lo(hv.x), alpha, acc0);
            acc1 = fmaf(bf2f_hi(hv.x), alpha, acc1);
            acc2 = fmaf(bf2f_lo(hv.y), alpha, acc2);
            acc3 = fmaf(bf2f_hi(hv.y), alpha, acc3);
        }
        float4 o;
        o.x = acc0 + bias[cbase + 0];
        o.y = acc1 + bias[cbase + 1];
        o.z = acc2 + bias[cbase + 2];
        o.w = acc3 + bias[cbase + 3];
        if (TANH) {
            o.x = tanhf(o.x); o.y = tanhf(o.y); o.z = tanhf(o.z); o.w = tanhf(o.w);
        }
        if (OB16) {
            ushort4 v;
            v.x = f2bf(o.x); v.y = f2bf(o.y); v.z = f2bf(o.z); v.w = f2bf(o.w);
            *reinterpret_cast<ushort4*>(out16 + (size_t)node * HCv + cbase) = v;
        } else {
            *reinterpret_cast<float4*>(outf + (size_t)node * HCv + cbase) = o;
        }
    }
}

// ---------------- final linear (256 -> 2) + softmax ----------------

__global__ void final_k(const float* __restrict__ h, const float* __restrict__ Wl,
                        const float* __restrict__ bl, float* __restrict__ out) {
    int lane = threadIdx.x & 63;
    int node = blockIdx.x * 4 + (threadIdx.x >> 6);
    if (node >= N_NODES) return;
    const float* hr = h + (size_t)node * HCv;
    float o0 = 0.f, o1 = 0.f;
    for (int k = lane; k < HCv; k += 64) {
        float v = hr[k];
        o0 += v * Wl[k * 2 + 0];
        o1 += v * Wl[k * 2 + 1];
    }
#pragma unroll
    for (int off = 32; off; off >>= 1) {
        o0 += __shfl_down(o0, off);
        o1 += __shfl_down(o1, off);
    }
    if (lane == 0) {
        o0 += bl[0];
        o1 += bl[1];
        float mx = fmaxf(o0, o1);
        float e0 = __expf(o0 - mx), e1 = __expf(o1 - mx);
        float inv = 1.f / (e0 + e1);
        out[node * 2 + 0] = e0 * inv;
        out[node * 2 + 1] = e1 * inv;
    }
}

// ---------------- launch ----------------

extern "C" void kernel_launch(void* const* d_in, const int* in_sizes, int n_in,
                              void* d_out, int out_size, void* d_ws, size_t ws_size,
                              hipStream_t stream) {
    const float* x        = (const float*)d_in[0];
    const int*   ei       = (const int*)d_in[1];
    const float* W0       = (const float*)d_in[2];
    const float* att_src0 = (const float*)d_in[3];
    const float* att_dst0 = (const float*)d_in[4];
    const float* b0       = (const float*)d_in[5];
    const float* W1       = (const float*)d_in[6];
    const float* att_src1 = (const float*)d_in[7];
    const float* att_dst1 = (const float*)d_in[8];
    const float* b1       = (const float*)d_in[9];
    const float* Wl       = (const float*)d_in[10];
    const float* bl       = (const float*)d_in[11];
    float* out = (float*)d_out;

    // workspace layout
    float* fbuf = (float*)d_ws;                                   // N*256 f32 (layer1 agg out; front reused as xb)
    unsigned short* xb = (unsigned short*)d_ws;                   // N*128 bf16 (dead before fbuf written)
    unsigned short* h16 = (unsigned short*)(fbuf + (size_t)N_NODES * HCv);     // N*256 bf16 (gemm out)
    unsigned short* hact16 = h16 + (size_t)N_NODES * HCv;         // N*256 bf16 (layer0 agg out)
    unsigned short* WT0 = hact16 + (size_t)N_NODES * HCv;         // 256*128 bf16
    unsigned short* WT1 = WT0 + 256 * 128;                        // 256*256 bf16
    float* a_s  = (float*)(WT1 + 256 * 256);                      // N*2
    float* a_d  = a_s + N_NODES * 2;                              // N*2
    int* deg    = (int*)(a_d + N_NODES * 2);                      // N
    int* total  = deg + N_NODES;                                  // 1
    int* start  = total + 1;                                      // N
    int* cursor = start + N_NODES;                                // N
    int* colv   = cursor + N_NODES;                               // E + N

    // ---- prep: bf16 conversions ----
    cvt_bf16_k<<<(N_NODES * 128 / 4 + 255) / 256, 256, 0, stream>>>(x, xb, N_NODES * 128 / 4);
    wt_k<<<128, 256, 0, stream>>>(W0, WT0, 128);
    wt_k<<<256, 256, 0, stream>>>(W1, WT1, 256);

    // ---- CSR build ----
    hipMemsetAsync(deg, 0, (N_NODES + 1) * sizeof(int), stream);
    int eb = (TOT_E + 255) / 256;
    count_deg_k<<<eb, 256, 0, stream>>>(ei, deg);
    offsets_k<<<(N_NODES + 255) / 256, 256, 0, stream>>>(deg, start, cursor, total);
    scatter_k<<<eb, 256, 0, stream>>>(ei, cursor, colv);

    dim3 ggrid(4, (N_NODES + 127) / 128);
    int nn4 = (N_NODES + 3) / 4;

    // ---- layer 0 ----
    hipMemsetAsync(a_s, 0, (size_t)N_NODES * 4 * sizeof(float), stream);
    mfma_gemm_att_k<128><<<ggrid, 256, 0, stream>>>(xb, WT0, h16, att_src0, att_dst0,
                                                    a_s, a_d, N_NODES);
    agg_k<true, true><<<nn4, 256, 0, stream>>>(h16, a_s, a_d, start, deg, colv, b0,
                                               nullptr, hact16);

    // ---- layer 1 ----
    hipMemsetAsync(a_s, 0, (size_t)N_NODES * 4 * sizeof(float), stream);
    mfma_gemm_att_k<256><<<ggrid, 256, 0, stream>>>(hact16, WT1, h16, att_src1, att_dst1,
                                                    a_s, a_d, N_NODES);
    agg_k<false, false><<<nn4, 256, 0, stream>>>(h16, a_s, a_d, start, deg, colv, b1,
                                                 fbuf, nullptr);

    // ---- final linear + softmax ----
    final_k<<<nn4, 256, 0, stream>>>(fbuf, Wl, bl, out);
}

// Round 6
// 343.089 us; speedup vs baseline: 2.0386x; 1.0411x over previous
//
#include <hip/hip_runtime.h>
#include <math.h>

// Problem constants (from reference)
constexpr int N_NODES = 50000;
constexpr int N_EDGES = 800000;
constexpr int TOT_E   = N_EDGES + N_NODES;   // + self loops
constexpr int HCv     = 256;                 // H*C
constexpr int MAXD    = 256;                 // LDS logit-cache capacity per wave

typedef __attribute__((ext_vector_type(8))) short bf16x8;
typedef __attribute__((ext_vector_type(4))) float f32x4;

// ---- bf16 helpers (manual RNE, deterministic) ----
__device__ __forceinline__ unsigned short f2bf(float f) {
    unsigned int u = __float_as_uint(f);
    unsigned int r = (u + 0x7fffu + ((u >> 16) & 1u)) >> 16;
    return (unsigned short)r;
}
__device__ __forceinline__ unsigned int f2bf_pack(float lo, float hi) {
    return (unsigned int)f2bf(lo) | ((unsigned int)f2bf(hi) << 16);
}
__device__ __forceinline__ float bf2f_lo(unsigned int packed) {
    return __uint_as_float(packed << 16);
}
__device__ __forceinline__ float bf2f_hi(unsigned int packed) {
    return __uint_as_float(packed & 0xffff0000u);
}

// ---------------- prep: fp32 -> bf16 convert / weight transpose ----------------

__global__ void cvt_bf16_k(const float* __restrict__ in, unsigned short* __restrict__ out,
                           int n4) {
    int i = blockIdx.x * blockDim.x + threadIdx.x;
    if (i >= n4) return;
    float4 v = *reinterpret_cast<const float4*>(in + (size_t)i * 4);
    ushort4 o;
    o.x = f2bf(v.x); o.y = f2bf(v.y); o.z = f2bf(v.z); o.w = f2bf(v.w);
    *reinterpret_cast<ushort4*>(out + (size_t)i * 4) = o;
}

// WT[n][k] = bf16(W[k][n]);  W is [K][256]
__global__ void wt_k(const float* __restrict__ W, unsigned short* __restrict__ WT, int K) {
    int idx = blockIdx.x * 256 + threadIdx.x;
    if (idx >= K * 256) return;
    int k = idx >> 8, n = idx & 255;
    WT[(size_t)n * K + k] = f2bf(W[idx]);
}

// ---------------- CSR build ----------------

__global__ void count_deg_k(const int* __restrict__ ei, int* __restrict__ deg) {
    int e = blockIdx.x * blockDim.x + threadIdx.x;
    if (e >= TOT_E) return;
    int dst = (e < N_EDGES) ? ei[N_EDGES + e] : (e - N_EDGES);
    atomicAdd(&deg[dst], 1);
}

__global__ void offsets_k(const int* __restrict__ deg, int* __restrict__ start,
                          int* __restrict__ cursor, int* __restrict__ total) {
    int lane = threadIdx.x & 63;
    int node = blockIdx.x * blockDim.x + threadIdx.x;
    int d = (node < N_NODES) ? deg[node] : 0;
    int pre = d;
#pragma unroll
    for (int off = 1; off < 64; off <<= 1) {
        int v = __shfl_up(pre, off);
        if (lane >= off) pre += v;
    }
    int wtot = __shfl(pre, 63);
    int base = 0;
    if (lane == 63) base = atomicAdd(total, wtot);
    base = __shfl(base, 63);
    int my = base + pre - d;
    if (node < N_NODES) { start[node] = my; cursor[node] = my; }
}

__global__ void scatter_k(const int* __restrict__ ei, int* __restrict__ cursor,
                          int* __restrict__ colv) {
    int e = blockIdx.x * blockDim.x + threadIdx.x;
    if (e >= TOT_E) return;
    int srcv, dstv;
    if (e < N_EDGES) { srcv = ei[e]; dstv = ei[N_EDGES + e]; }
    else             { srcv = dstv = e - N_EDGES; }
    int pos = atomicAdd(&cursor[dstv], 1);
    colv[pos] = srcv;
}

// ---------------- MFMA bf16 GEMM + fused attention epilogue ----------------

template <int K>
__global__ __launch_bounds__(256) void mfma_gemm_att_k(
        const unsigned short* __restrict__ A,   // [M][K] bf16
        const unsigned short* __restrict__ BT,  // [256][K] bf16 (W transposed)
        unsigned short* __restrict__ h16,       // [M][256] bf16 out
        const float* __restrict__ att_src, const float* __restrict__ att_dst,
        float* __restrict__ a_s, float* __restrict__ a_d, int M) {
    const int lane = threadIdx.x & 63;
    const int wv = threadIdx.x >> 6;
    const int lm = lane & 15;
    const int g8 = (lane >> 4) * 8;
    const int row0 = blockIdx.y * 128 + wv * 32;
    const int n0 = blockIdx.x * 64;

    int ra0 = row0 + lm;       if (ra0 >= M) ra0 = M - 1;
    int ra1 = row0 + 16 + lm;  if (ra1 >= M) ra1 = M - 1;
    const unsigned short* pa0 = A + (size_t)ra0 * K + g8;
    const unsigned short* pa1 = A + (size_t)ra1 * K + g8;
    const unsigned short* pb  = BT + (size_t)(n0 + lm) * K + g8;

    f32x4 acc[2][4] = {};
#pragma unroll
    for (int kt = 0; kt < K; kt += 32) {
        bf16x8 a0 = *reinterpret_cast<const bf16x8*>(pa0 + kt);
        bf16x8 a1 = *reinterpret_cast<const bf16x8*>(pa1 + kt);
        bf16x8 b0 = *reinterpret_cast<const bf16x8*>(pb + kt);
        bf16x8 b1 = *reinterpret_cast<const bf16x8*>(pb + 16 * K + kt);
        bf16x8 b2 = *reinterpret_cast<const bf16x8*>(pb + 32 * K + kt);
        bf16x8 b3 = *reinterpret_cast<const bf16x8*>(pb + 48 * K + kt);
        acc[0][0] = __builtin_amdgcn_mfma_f32_16x16x32_bf16(a0, b0, acc[0][0], 0, 0, 0);
        acc[0][1] = __builtin_amdgcn_mfma_f32_16x16x32_bf16(a0, b1, acc[0][1], 0, 0, 0);
        acc[0][2] = __builtin_amdgcn_mfma_f32_16x16x32_bf16(a0, b2, acc[0][2], 0, 0, 0);
        acc[0][3] = __builtin_amdgcn_mfma_f32_16x16x32_bf16(a0, b3, acc[0][3], 0, 0, 0);
        acc[1][0] = __builtin_amdgcn_mfma_f32_16x16x32_bf16(a1, b0, acc[1][0], 0, 0, 0);
        acc[1][1] = __builtin_amdgcn_mfma_f32_16x16x32_bf16(a1, b1, acc[1][1], 0, 0, 0);
        acc[1][2] = __builtin_amdgcn_mfma_f32_16x16x32_bf16(a1, b2, acc[1][2], 0, 0, 0);
        acc[1][3] = __builtin_amdgcn_mfma_f32_16x16x32_bf16(a1, b3, acc[1][3], 0, 0, 0);
    }

    float as_c[4], ad_c[4];
#pragma unroll
    for (int j = 0; j < 4; ++j) {
        int c = n0 + j * 16 + lm;
        as_c[j] = att_src[c];
        ad_c[j] = att_dst[c];
    }
    const int head = n0 >> 7;

#pragma unroll
    for (int i = 0; i < 2; ++i) {
        float ps[4] = {}, pd[4] = {};
#pragma unroll
        for (int j = 0; j < 4; ++j)
#pragma unroll
            for (int r = 0; r < 4; ++r) {
                ps[r] += acc[i][j][r] * as_c[j];
                pd[r] += acc[i][j][r] * ad_c[j];
            }
#pragma unroll
        for (int off = 1; off < 16; off <<= 1)
#pragma unroll
            for (int r = 0; r < 4; ++r) {
                ps[r] += __shfl_xor(ps[r], off);
                pd[r] += __shfl_xor(pd[r], off);
            }
        if (lm == 0) {
            int rb = row0 + i * 16 + (lane >> 4) * 4;
#pragma unroll
            for (int r = 0; r < 4; ++r) {
                if (rb + r < M) {
                    atomicAdd(&a_s[(rb + r) * 2 + head], ps[r]);
                    atomicAdd(&a_d[(rb + r) * 2 + head], pd[r]);
                }
            }
        }
#pragma unroll
        for (int j = 0; j < 4; ++j)
#pragma unroll
            for (int r = 0; r < 4; ++r) {
                int row = row0 + i * 16 + (lane >> 4) * 4 + r;
                if (row < M)
                    h16[(size_t)row * HCv + n0 + j * 16 + lm] = f2bf(acc[i][j][r]);
            }
    }
}

// ---------------- aggregation: one wave per destination node ----------------
// Fast path: max-free softmax (logits are O(8), exp safe in fp32 — alpha is
// mathematically identical); fused gather+exp pass; pass B does 4 edges/iter
// (quarter-wave x 2 uint4) with guard-free main loop.

__device__ __forceinline__ float lrelu(float x) { return x > 0.f ? x : 0.2f * x; }

template <bool TANH, bool OB16>
__global__ __launch_bounds__(256) void agg_k(const unsigned short* __restrict__ h16,
                      const float* __restrict__ a_s, const float* __restrict__ a_d,
                      const int* __restrict__ start, const int* __restrict__ deg,
                      const int* __restrict__ colv, const float* __restrict__ bias,
                      float* __restrict__ outf, unsigned short* __restrict__ out16) {
    __shared__ float lexp[4][MAXD][2];
    const int lane = threadIdx.x & 63;
    const int wslot = threadIdx.x >> 6;
    const int node = blockIdx.x * 4 + wslot;
    if (node >= N_NODES) return;
    const int beg = start[node];
    const int degv = deg[node];
    const float ad0 = a_d[node * 2], ad1 = a_d[node * 2 + 1];
    const int* __restrict__ col = colv + beg;

    if (degv <= MAXD) {
        // ---- pass A: gather a_s, exp (max-free), stash to LDS, sum ----
        float s0 = 0.f, s1 = 0.f;
        for (int j = lane; j < degv; j += 64) {
            int s = col[j];
            float2 av = *reinterpret_cast<const float2*>(a_s + s * 2);
            float e0 = __expf(lrelu(av.x + ad0));
            float e1 = __expf(lrelu(av.y + ad1));
            *reinterpret_cast<float2*>(&lexp[wslot][j][0]) = make_float2(e0, e1);
            s0 += e0;
            s1 += e1;
        }
#pragma unroll
        for (int off = 32; off; off >>= 1) {
            s0 += __shfl_xor(s0, off);
            s1 += __shfl_xor(s1, off);
        }
        const float inv0 = 1.f / (s0 + 1e-16f);
        const float inv1 = 1.f / (s1 + 1e-16f);

        // ---- pass B: 4 edges/iter; quarter q owns edge 4i+q; lane covers
        // 16 channels [lq*16, lq*16+16) (single head per lane) ----
        const int q = lane >> 4;
        const int lq = lane & 15;
        const int cb = lq * 16;
        const int head = lq >> 3;
        const float invh = head ? inv1 : inv0;
        const unsigned short* __restrict__ hp = h16 + cb;
        float acc[16] = {};
        const int full = degv >> 2;
        for (int i = 0; i < full; ++i) {
            const int j = 4 * i + q;
            const int s = col[j];
            const float alpha = lexp[wslot][j][head] * invh;
            const uint4* p = reinterpret_cast<const uint4*>(hp + (size_t)s * HCv);
            const uint4 h0 = p[0];
            const uint4 h1 = p[1];
            acc[0]  = fmaf(bf2f_lo(h0.x), alpha, acc[0]);
            acc[1]  = fmaf(bf2f_hi(h0.x), alpha, acc[1]);
            acc[2]  = fmaf(bf2f_lo(h0.y), alpha, acc[2]);
            acc[3]  = fmaf(bf2f_hi(h0.y), alpha, acc[3]);
            acc[4]  = fmaf(bf2f_lo(h0.z), alpha, acc[4]);
            acc[5]  = fmaf(bf2f_hi(h0.z), alpha, acc[5]);
            acc[6]  = fmaf(bf2f_lo(h0.w), alpha, acc[6]);
            acc[7]  = fmaf(bf2f_hi(h0.w), alpha, acc[7]);
            acc[8]  = fmaf(bf2f_lo(h1.x), alpha, acc[8]);
            acc[9]  = fmaf(bf2f_hi(h1.x), alpha, acc[9]);
            acc[10] = fmaf(bf2f_lo(h1.y), alpha, acc[10]);
            acc[11] = fmaf(bf2f_hi(h1.y), alpha, acc[11]);
            acc[12] = fmaf(bf2f_lo(h1.z), alpha, acc[12]);
            acc[13] = fmaf(bf2f_hi(h1.z), alpha, acc[13]);
            acc[14] = fmaf(bf2f_lo(h1.w), alpha, acc[14]);
            acc[15] = fmaf(bf2f_hi(h1.w), alpha, acc[15]);
        }
        {   // tail (degv & 3 edges)
            const int j = full * 4 + q;
            if (j < degv) {
                const int s = col[j];
                const float alpha = lexp[wslot][j][head] * invh;
                const uint4* p = reinterpret_cast<const uint4*>(hp + (size_t)s * HCv);
                const uint4 h0 = p[0];
                const uint4 h1 = p[1];
                acc[0]  = fmaf(bf2f_lo(h0.x), alpha, acc[0]);
                acc[1]  = fmaf(bf2f_hi(h0.x), alpha, acc[1]);
                acc[2]  = fmaf(bf2f_lo(h0.y), alpha, acc[2]);
                acc[3]  = fmaf(bf2f_hi(h0.y), alpha, acc[3]);
                acc[4]  = fmaf(bf2f_lo(h0.z), alpha, acc[4]);
                acc[5]  = fmaf(bf2f_hi(h0.z), alpha, acc[5]);
                acc[6]  = fmaf(bf2f_lo(h0.w), alpha, acc[6]);
                acc[7]  = fmaf(bf2f_hi(h0.w), alpha, acc[7]);
                acc[8]  = fmaf(bf2f_lo(h1.x), alpha, acc[8]);
                acc[9]  = fmaf(bf2f_hi(h1.x), alpha, acc[9]);
                acc[10] = fmaf(bf2f_lo(h1.y), alpha, acc[10]);
                acc[11] = fmaf(bf2f_hi(h1.y), alpha, acc[11]);
                acc[12] = fmaf(bf2f_lo(h1.z), alpha, acc[12]);
                acc[13] = fmaf(bf2f_hi(h1.z), alpha, acc[13]);
                acc[14] = fmaf(bf2f_lo(h1.w), alpha, acc[14]);
                acc[15] = fmaf(bf2f_hi(h1.w), alpha, acc[15]);
            }
        }
#pragma unroll
        for (int c = 0; c < 16; ++c) {
            acc[c] += __shfl_xor(acc[c], 16);
            acc[c] += __shfl_xor(acc[c], 32);
        }
        if (lane < 16) {
#pragma unroll
            for (int c = 0; c < 16; ++c) acc[c] += bias[cb + c];
            if (TANH) {
#pragma unroll
                for (int c = 0; c < 16; ++c) acc[c] = tanhf(acc[c]);
            }
            if (OB16) {
                uint4 v0, v1;
                v0.x = f2bf_pack(acc[0], acc[1]);
                v0.y = f2bf_pack(acc[2], acc[3]);
                v0.z = f2bf_pack(acc[4], acc[5]);
                v0.w = f2bf_pack(acc[6], acc[7]);
                v1.x = f2bf_pack(acc[8], acc[9]);
                v1.y = f2bf_pack(acc[10], acc[11]);
                v1.z = f2bf_pack(acc[12], acc[13]);
                v1.w = f2bf_pack(acc[14], acc[15]);
                uint4* o = reinterpret_cast<uint4*>(out16 + (size_t)node * HCv + cb);
                o[0] = v0;
                o[1] = v1;
            } else {
                float4* o = reinterpret_cast<float4*>(outf + (size_t)node * HCv + cb);
                o[0] = make_float4(acc[0], acc[1], acc[2], acc[3]);
                o[1] = make_float4(acc[4], acc[5], acc[6], acc[7]);
                o[2] = make_float4(acc[8], acc[9], acc[10], acc[11]);
                o[3] = make_float4(acc[12], acc[13], acc[14], acc[15]);
            }
        }
    } else {
        // ---- fallback: 3-pass recompute path (deg > MAXD) ----
        const int end = beg + degv;
        float m0 = -INFINITY, m1 = -INFINITY;
        for (int e = beg + lane; e < end; e += 64) {
            int s = colv[e];
            m0 = fmaxf(m0, lrelu(a_s[s * 2] + ad0));
            m1 = fmaxf(m1, lrelu(a_s[s * 2 + 1] + ad1));
        }
#pragma unroll
        for (int off = 32; off; off >>= 1) {
            m0 = fmaxf(m0, __shfl_xor(m0, off));
            m1 = fmaxf(m1, __shfl_xor(m1, off));
        }
        float s0 = 0.f, s1 = 0.f;
        for (int e = beg + lane; e < end; e += 64) {
            int s = colv[e];
            s0 += __expf(lrelu(a_s[s * 2] + ad0) - m0);
            s1 += __expf(lrelu(a_s[s * 2 + 1] + ad1) - m1);
        }
#pragma unroll
        for (int off = 32; off; off >>= 1) {
            s0 += __shfl_xor(s0, off);
            s1 += __shfl_xor(s1, off);
        }
        float inv0 = 1.f / (s0 + 1e-16f);
        float inv1 = 1.f / (s1 + 1e-16f);
        const int head = lane >> 5;
        const float mh  = head ? m1 : m0;
        const float ih  = head ? inv1 : inv0;
        const float adh = head ? ad1 : ad0;
        const int cbase = lane * 4;
        float acc0 = 0.f, acc1 = 0.f, acc2 = 0.f, acc3 = 0.f;
        for (int e = beg; e < end; ++e) {
            int s = colv[e];
            float l = lrelu(a_s[s * 2 + head] + adh);
            float alpha = __expf(l - mh) * ih;
            uint2 hv = *reinterpret_cast<const uint2*>(h16 + (size_t)s * HCv + cbase);
            acc0 = fmaf(bf2f_lo(hv.x), alpha, acc0);
            acc1 = fmaf(bf2f_hi(hv.x), alpha, acc1);
            acc2 = fmaf(bf2f_lo(hv.y), alpha, acc2);
            acc3 = fmaf(bf2f_hi(hv.y), alpha, acc3);
        }
        float4 o;
        o.x = acc0 + bias[cbase + 0];
        o.y = acc1 + bias[cbase + 1];
        o.z = acc2 + bias[cbase + 2];
        o.w = acc3 + bias[cbase + 3];
        if (TANH) {
            o.x = tanhf(o.x); o.y = tanhf(o.y); o.z = tanhf(o.z); o.w = tanhf(o.w);
        }
        if (OB16) {
            ushort4 v;
            v.x = f2bf(o.x); v.y = f2bf(o.y); v.z = f2bf(o.z); v.w = f2bf(o.w);
            *reinterpret_cast<ushort4*>(out16 + (size_t)node * HCv + cbase) = v;
        } else {
            *reinterpret_cast<float4*>(outf + (size_t)node * HCv + cbase) = o;
        }
    }
}

// ---------------- final linear (256 -> 2) + softmax ----------------

__global__ void final_k(const float* __restrict__ h, const float* __restrict__ Wl,
                        const float* __restrict__ bl, float* __restrict__ out) {
    int lane = threadIdx.x & 63;
    int node = blockIdx.x * 4 + (threadIdx.x >> 6);
    if (node >= N_NODES) return;
    const float* hr = h + (size_t)node * HCv;
    float o0 = 0.f, o1 = 0.f;
    for (int k = lane; k < HCv; k += 64) {
        float v = hr[k];
        o0 += v * Wl[k * 2 + 0];
        o1 += v * Wl[k * 2 + 1];
    }
#pragma unroll
    for (int off = 32; off; off >>= 1) {
        o0 += __shfl_down(o0, off);
        o1 += __shfl_down(o1, off);
    }
    if (lane == 0) {
        o0 += bl[0];
        o1 += bl[1];
        float mx = fmaxf(o0, o1);
        float e0 = __expf(o0 - mx), e1 = __expf(o1 - mx);
        float inv = 1.f / (e0 + e1);
        out[node * 2 + 0] = e0 * inv;
        out[node * 2 + 1] = e1 * inv;
    }
}

// ---------------- launch ----------------

extern "C" void kernel_launch(void* const* d_in, const int* in_sizes, int n_in,
                              void* d_out, int out_size, void* d_ws, size_t ws_size,
                              hipStream_t stream) {
    const float* x        = (const float*)d_in[0];
    const int*   ei       = (const int*)d_in[1];
    const float* W0       = (const float*)d_in[2];
    const float* att_src0 = (const float*)d_in[3];
    const float* att_dst0 = (const float*)d_in[4];
    const float* b0       = (const float*)d_in[5];
    const float* W1       = (const float*)d_in[6];
    const float* att_src1 = (const float*)d_in[7];
    const float* att_dst1 = (const float*)d_in[8];
    const float* b1       = (const float*)d_in[9];
    const float* Wl       = (const float*)d_in[10];
    const float* bl       = (const float*)d_in[11];
    float* out = (float*)d_out;

    // workspace layout
    float* fbuf = (float*)d_ws;                                   // N*256 f32 (layer1 agg out; front reused as xb)
    unsigned short* xb = (unsigned short*)d_ws;                   // N*128 bf16 (dead before fbuf written)
    unsigned short* h16 = (unsigned short*)(fbuf + (size_t)N_NODES * HCv);     // N*256 bf16 (gemm out)
    unsigned short* hact16 = h16 + (size_t)N_NODES * HCv;         // N*256 bf16 (layer0 agg out)
    unsigned short* WT0 = hact16 + (size_t)N_NODES * HCv;         // 256*128 bf16
    unsigned short* WT1 = WT0 + 256 * 128;                        // 256*256 bf16
    float* a_s  = (float*)(WT1 + 256 * 256);                      // N*2
    float* a_d  = a_s + N_NODES * 2;                              // N*2
    int* deg    = (int*)(a_d + N_NODES * 2);                      // N
    int* total  = deg + N_NODES;                                  // 1
    int* start  = total + 1;                                      // N
    int* cursor = start + N_NODES;                                // N
    int* colv   = cursor + N_NODES;                               // E + N

    // ---- prep: bf16 conversions ----
    cvt_bf16_k<<<(N_NODES * 128 / 4 + 255) / 256, 256, 0, stream>>>(x, xb, N_NODES * 128 / 4);
    wt_k<<<128, 256, 0, stream>>>(W0, WT0, 128);
    wt_k<<<256, 256, 0, stream>>>(W1, WT1, 256);

    // ---- CSR build ----
    hipMemsetAsync(deg, 0, (N_NODES + 1) * sizeof(int), stream);
    int eb = (TOT_E + 255) / 256;
    count_deg_k<<<eb, 256, 0, stream>>>(ei, deg);
    offsets_k<<<(N_NODES + 255) / 256, 256, 0, stream>>>(deg, start, cursor, total);
    scatter_k<<<eb, 256, 0, stream>>>(ei, cursor, colv);

    dim3 ggrid(4, (N_NODES + 127) / 128);
    int nn4 = (N_NODES + 3) / 4;

    // ---- layer 0 ----
    hipMemsetAsync(a_s, 0, (size_t)N_NODES * 4 * sizeof(float), stream);
    mfma_gemm_att_k<128><<<ggrid, 256, 0, stream>>>(xb, WT0, h16, att_src0, att_dst0,
                                                    a_s, a_d, N_NODES);
    agg_k<true, true><<<nn4, 256, 0, stream>>>(h16, a_s, a_d, start, deg, colv, b0,
                                               nullptr, hact16);

    // ---- layer 1 ----
    hipMemsetAsync(a_s, 0, (size_t)N_NODES * 4 * sizeof(float), stream);
    mfma_gemm_att_k<256><<<ggrid, 256, 0, stream>>>(hact16, WT1, h16, att_src1, att_dst1,
                                                    a_s, a_d, N_NODES);
    agg_k<false, false><<<nn4, 256, 0, stream>>>(h16, a_s, a_d, start, deg, colv, b1,
                                                 fbuf, nullptr);

    // ---- final linear + softmax ----
    final_k<<<nn4, 256, 0, stream>>>(fbuf, Wl, bl, out);
}